// Round 1
// baseline (458.885 us; speedup 1.0000x reference)
//
#include <hip/hip_runtime.h>
#include <cstdint>
#include <cstddef>

// StripedHyena layer on MI355X.
// R6: gemm_conv ported from the 128^2 2-barrier structure (~830 TF plateau,
// MfmaUtil 36%) to the 256^2 / BK=64 / 8-wave / 8-phase counted-vmcnt schedule
// (T2 swizzle + T3/T4 counted vmcnt(4) + T5 setprio). vmcnt never drains to 0
// in the main loop; 2 half-tiles stay in flight across barriers. Heavy conv
// (taps=15) dispatched first for load balance. Everything else unchanged.

#define B_ 8
#define L_ 4096
#define D_ 256
#define H_ 768
#define NST 32
#define LC 128
#define NC 32

typedef _Float16 f16;
typedef _Float16 f16x8 __attribute__((ext_vector_type(8)));
typedef _Float16 f16x4 __attribute__((ext_vector_type(4)));
typedef _Float16 f16x2 __attribute__((ext_vector_type(2)));
typedef float f32x4 __attribute__((ext_vector_type(4)));

__device__ __forceinline__ f32x4 mfma16(f16x8 a, f16x8 b, f32x4 c) {
  return __builtin_amdgcn_mfma_f32_16x16x32_f16(a, b, c, 0, 0, 0);
}

#define GLDS16(g, l)                                                              \
  __builtin_amdgcn_global_load_lds((const __attribute__((address_space(1))) void*)(g), \
                                   (__attribute__((address_space(3))) void*)(l), 16, 0, 0)

// ---------------- fused prep: casts + zero buffer + conv A-matrix ----------------
__global__ __launch_bounds__(256) void prep_all(
    const float* __restrict__ x, const float* __restrict__ gate_w,
    const float* __restrict__ res_w,
    const float* __restrict__ w0, const float* __restrict__ w1, const float* __restrict__ w2,
    f16* __restrict__ xh, f16* __restrict__ Ag, float* __restrict__ zbuf,
    f16* __restrict__ A) {
  int bid = blockIdx.x, tid = threadIdx.x;
  if (bid < 8192) {            // cast x -> xh
    int i = (bid * 256 + tid) * 4;
    float4 v = *(const float4*)(x + i);
    xh[i+0]=(f16)v.x; xh[i+1]=(f16)v.y; xh[i+2]=(f16)v.z; xh[i+3]=(f16)v.w;
  } else if (bid < 8384) {     // cast gate_w
    int i = ((bid - 8192) * 256 + tid) * 4;
    float4 v = *(const float4*)(gate_w + i);
    Ag[i+0]=(f16)v.x; Ag[i+1]=(f16)v.y; Ag[i+2]=(f16)v.z; Ag[i+3]=(f16)v.w;
  } else if (bid < 8576) {     // cast res_w
    int i = ((bid - 8384) * 256 + tid) * 4;
    float4 v = *(const float4*)(res_w + i);
    f16* d = Ag + 768 * 256;
    d[i+0]=(f16)v.x; d[i+1]=(f16)v.y; d[i+2]=(f16)v.z; d[i+3]=(f16)v.w;
  } else if (bid == 8576) {    // zero buffer for OOB dilation rows
    zbuf[tid] = 0.f;
  } else {                     // conv weights -> A[o][t*256+j] layout
    int idx = (bid - 8577) * 256 + tid;   // exactly 1,638,400
    const int n0 = 256 * 256 * 3, n1 = 256 * 256 * 7;
    const float* w; int K, base;
    if (idx < n0) { w = w0; K = 3; base = 0; }
    else if (idx < n0 + n1) { idx -= n0; w = w1; K = 7; base = 256 * 768; }
    else { idx -= n0 + n1; w = w2; K = 15; base = 256 * 768 + 256 * 1792; }
    int o = idx / (256 * K); int r = idx - o * (256 * K); int j = r / K; int t = r - j * K;
    A[base + o * (256 * K) + t * 256 + j] = (f16)w[idx];
  }
}

// ---------------- fused S4D parameter build ----------------
__global__ __launch_bounds__(256) void s4_all(const float* __restrict__ log_dt,
                                              const float* __restrict__ A_re,
                                              const float* __restrict__ A_im,
                                              const float* __restrict__ C_re,
                                              const float* __restrict__ C_im,
                                              f16* __restrict__ A1, f16* __restrict__ A2,
                                              float* __restrict__ WLc,
                                              float* __restrict__ kT) {
  int bid = blockIdx.x, tid = threadIdx.x;
  if (bid < 96) {
    int idx = bid * 256 + tid;  // h*32+n
    int h = idx >> 5, n = idx & 31;
    float dt = expf(log_dt[h]);
    float Ar = A_re[idx], Ai = A_im[idx];
    float ar = dt * Ar, ai = dt * Ai;
    float e = expf(ar), sn, cs; sincosf(ai, &sn, &cs);
    float wr = e * cs, wi = e * sn;                 // w = exp(dt*A)
    float den = Ar * Ar + Ai * Ai;
    float Er = wr - 1.f, Ei = wi;
    float Cr = C_re[idx], Ci = C_im[idx];
    float nr = Cr * Er - Ci * Ei, ni = Cr * Ei + Ci * Er;
    float Cdr = (nr * Ar + ni * Ai) / den;          // C_disc = C*(w-1)/A
    float Cdi = (ni * Ar - nr * Ai) / den;
    f16* A1r = A1 + ((size_t)h * 64 + 2 * n) * LC;
    f16* A1i = A1 + ((size_t)h * 64 + 2 * n + 1) * LC;
    float pr = 1.f, pi = 0.f;
    for (int j = 0; j < LC; ++j) {
      A1r[LC - 1 - j] = (f16)pr; A1i[LC - 1 - j] = (f16)pi;
      float t0 = pr * wr - pi * wi; pi = pr * wi + pi * wr; pr = t0;
    }
    WLc[idx * 2] = pr; WLc[idx * 2 + 1] = pi;       // w^128
    float qr = wr, qi = wi;
    for (int t = 0; t < LC; ++t) {
      A2[((size_t)h * LC + t) * 64 + 2 * n]     = (f16)(2.f * (Cdr * qr - Cdi * qi));
      A2[((size_t)h * LC + t) * 64 + 2 * n + 1] = (f16)(-2.f * (Cdr * qi + Cdi * qr));
      float t0 = qr * wr - qi * wi; qi = qr * wi + qi * wr; qr = t0;
    }
  } else {
    int idx = (bid - 96) * 256 + tid;  // h*128+j
    int h = idx >> 7, j = idx & 127;
    float dt = expf(log_dt[h]);
    float acc = 0.f;
    for (int n = 0; n < NST; ++n) {
      float Ar = A_re[h * 32 + n], Ai = A_im[h * 32 + n];
      float ar = dt * Ar, ai = dt * Ai;
      float e1 = expf(ar), s1, c1; sincosf(ai, &s1, &c1);
      float wr = e1 * c1, wi = e1 * s1;
      float den = Ar * Ar + Ai * Ai;
      float Er = wr - 1.f, Ei = wi;
      float Cr = C_re[h * 32 + n], Ci = C_im[h * 32 + n];
      float nr = Cr * Er - Ci * Ei, ni = Cr * Ei + Ci * Er;
      float Cdr = (nr * Ar + ni * Ai) / den, Cdi = (ni * Ar - nr * Ai) / den;
      float ej = expf(ar * (float)j), sj, cj; sincosf(ai * (float)j, &sj, &cj);
      acc += 2.f * (Cdr * (ej * cj) - Cdi * (ej * sj));
    }
    kT[idx] = acc;
  }
}

// -------- GEMM 1: gate + res projections (K=256). grid (256, 12) --------
__global__ __launch_bounds__(256) void gemm_gr(
    const f16* __restrict__ xh, const f16* __restrict__ Agr,
    const float* __restrict__ gate_b, const float* __restrict__ res_b,
    f16* __restrict__ gts, f16* __restrict__ res) {
  __shared__ f16 As[128 * 64];
  __shared__ f16 Bs[128 * 64];
  const int mt = blockIdx.y, nt = blockIdx.x;
  const int b = nt >> 5, l0 = (nt & 31) * 128;
  const bool isg = mt < 6;
  const int hbase = (isg ? mt : mt - 6) * 128;
  const f16* Abase = Agr + (size_t)((isg ? 0 : 768) + hbase) * 256;
  const int tid = threadIdx.x;
  const int wid = tid >> 6, lane = tid & 63, l15 = lane & 15, quad = lane >> 4;
  const int wm = (wid & 1) * 64, wn = (wid >> 1) * 64;
  const int srow = (wid << 5) + (lane >> 3);
  const int sperm = ((lane & 7) ^ (lane >> 3)) << 3;
  char* AsL = (char*)As + (wid << 12);
  char* BsL = (char*)Bs + (wid << 12);
  const f16* xrow = xh + (((size_t)b * L_) << 8);

  f32x4 acc[4][4];
#pragma unroll
  for (int i = 0; i < 4; ++i)
#pragma unroll
    for (int j = 0; j < 4; ++j) acc[i][j] = (f32x4){0.f, 0.f, 0.f, 0.f};

  for (int kc = 0; kc < 4; ++kc) {
#pragma unroll
    for (int j = 0; j < 4; ++j) {
      int row = srow + j * 8;
      GLDS16(Abase + (size_t)row * 256 + kc * 64 + sperm, AsL + (j << 10));
      GLDS16(xrow + ((size_t)(l0 + row) << 8) + kc * 64 + sperm, BsL + (j << 10));
    }
    __syncthreads();
#pragma unroll
    for (int k2 = 0; k2 < 2; ++k2) {
      f16x8 af[4], bf[4];
#pragma unroll
      for (int mi = 0; mi < 4; ++mi) {
        int r = wm + mi * 16 + l15;
        af[mi] = *(const f16x8*)(&As[r * 64 + (((k2 * 4 + quad) ^ (r & 7)) << 3)]);
      }
#pragma unroll
      for (int ni = 0; ni < 4; ++ni) {
        int r = wn + ni * 16 + l15;
        bf[ni] = *(const f16x8*)(&Bs[r * 64 + (((k2 * 4 + quad) ^ (r & 7)) << 3)]);
      }
#pragma unroll
      for (int mi = 0; mi < 4; ++mi)
#pragma unroll
        for (int ni = 0; ni < 4; ++ni) acc[mi][ni] = mfma16(af[mi], bf[ni], acc[mi][ni]);
    }
    __syncthreads();
  }

  if (isg) {
#pragma unroll
    for (int mi = 0; mi < 4; ++mi)
#pragma unroll
      for (int ni = 0; ni < 4; ++ni) {
        int hg = hbase + wm + mi * 16 + quad * 4;
        int lg = l0 + wn + ni * 16 + l15;
#pragma unroll
        for (int r = 0; r < 4; ++r) {
          float val = acc[mi][ni][r] + gate_b[hg + r];
          gts[((size_t)(b * H_ + hg + r)) * L_ + lg] = (f16)(1.f / (1.f + expf(-val)));
        }
      }
  } else {
#pragma unroll
    for (int mi = 0; mi < 4; ++mi)
#pragma unroll
      for (int ni = 0; ni < 4; ++ni) {
        int hg = hbase + wm + mi * 16 + quad * 4;
        int lg = l0 + wn + ni * 16 + l15;
#pragma unroll
        for (int r = 0; r < 4; ++r)
          res[((size_t)(b * H_ + hg + r)) * L_ + lg] = (f16)(acc[mi][ni][r] + res_b[hg + r]);
      }
  }
}

// -------- GEMM 2: dilated convs, 256^2 tile, 8-phase counted-vmcnt schedule.
// grid (128, 3): y=0 -> taps=15 (heavy first), 512 threads, 128 KiB LDS,
// 1 block/CU. Per K-step (BK=64) 4 phases, one C-quadrant each; stages are
// staggered so vmcnt(4) (2 half-tiles in flight) covers every read. --------
__global__ __launch_bounds__(512, 2) void gemm_conv8(
    const f16* __restrict__ xh, const f16* __restrict__ Aconv,
    const float* __restrict__ cb0, const float* __restrict__ cb1, const float* __restrict__ cb2,
    const f16* __restrict__ gts, const f16* __restrict__ zbuf,
    f16* __restrict__ v) {
  __shared__ f16 lds[65536];     // A0 | B0 | A1 | B1, 16384 f16 each = 128 KiB
  f16* A0 = lds;
  f16* B0 = lds + 16384;
  f16* A1 = lds + 32768;
  f16* B1 = lds + 49152;

  const int nt = blockIdx.x;
  const int b = nt >> 4, l0 = (nt & 15) * 256;
  const int ci = 2 - blockIdx.y;           // heavy (taps=15) dispatched first
  const int tid = threadIdx.x;
  const int wid = tid >> 6, lane = tid & 63, l15 = lane & 15, quad = lane >> 4;
  const int wr = wid >> 2, wc = wid & 3;   // 2 (M) x 4 (N) wave grid
  const int r0 = tid >> 3;                 // stage row base (0..63)
  const int cswz = ((tid & 7) ^ ((tid >> 3) & 7)) << 3;  // stage src swizzle (f16)
  const int rsw = lane & 7;                // read-side swizzle
  const f16* xrow = xh + (((size_t)b * L_) << 8);

  const f16* Acb; int Krow, taps, dil;
  if (ci == 0)      { Acb = Aconv;                          Krow = 768;  taps = 3;  dil = 1; }
  else if (ci == 1) { Acb = Aconv + 256 * 768;              Krow = 1792; taps = 7;  dil = 2; }
  else              { Acb = Aconv + 256 * 768 + 256 * 1792; Krow = 3840; taps = 15; dil = 4; }
  const int KS = taps * 4;                 // K-steps of 64 (12 / 28 / 60)

  f32x4 acc[8][4];
#pragma unroll
  for (int i = 0; i < 8; ++i)
#pragma unroll
    for (int j = 0; j < 4; ++j) acc[i][j] = (f32x4){0.f, 0.f, 0.f, 0.f};
  f16x8 af[4][2], blo[2][2], bhi[2][2];

  // ---- staging helpers: 1 half-tile = [128 rows][64 k] = 2 x GLDS16/thread ----
  auto stageA = [&](int kst, int h, f16* Ad) {
    int t = kst >> 2, jb = (kst & 3) << 6;
    const f16* s0 = Acb + (size_t)(h * 128 + r0) * Krow + t * 256 + jb + cswz;
    GLDS16(s0, Ad + h * 8192 + wid * 512);
    GLDS16(s0 + (size_t)64 * Krow, Ad + h * 8192 + 4096 + wid * 512);
  };
  auto stageB = [&](int kst, int h, f16* Bd) {
    int t = kst >> 2, jb = (kst & 3) << 6;
    int boff = (t - (taps - 1) / 2) * dil;
    int gl0 = l0 + h * 128 + r0 + boff;
    const f16* s0 = (gl0 < 0 || gl0 >= L_) ? (zbuf + cswz)
                    : xrow + ((size_t)gl0 << 8) + jb + cswz;
    GLDS16(s0, Bd + h * 8192 + wid * 512);
    int gl1 = gl0 + 64;
    const f16* s1 = (gl1 < 0 || gl1 >= L_) ? (zbuf + cswz)
                    : xrow + ((size_t)gl1 << 8) + jb + cswz;
    GLDS16(s1, Bd + h * 8192 + 4096 + wid * 512);
  };
  auto loadA = [&](const f16* Ab, int MH) {
#pragma unroll
    for (int mi = 0; mi < 4; ++mi) {
      int r = MH * 128 + wr * 64 + mi * 16 + l15;
#pragma unroll
      for (int k2 = 0; k2 < 2; ++k2)
        af[mi][k2] = *(const f16x8*)(Ab + r * 64 + (((k2 * 4 + quad) ^ rsw) << 3));
    }
  };
  auto loadB = [&](const f16* Bb, int NH, f16x8 (&bf)[2][2]) {
#pragma unroll
    for (int ni = 0; ni < 2; ++ni) {
      int r = NH * 128 + wc * 32 + ni * 16 + l15;
#pragma unroll
      for (int k2 = 0; k2 < 2; ++k2)
        bf[ni][k2] = *(const f16x8*)(Bb + r * 64 + (((k2 * 4 + quad) ^ rsw) << 3));
    }
  };
  auto quadMM = [&](int MH, int NH, f16x8 (&bf)[2][2]) {
#pragma unroll
    for (int k2 = 0; k2 < 2; ++k2)
#pragma unroll
      for (int mi = 0; mi < 4; ++mi)
#pragma unroll
        for (int ni = 0; ni < 2; ++ni)
          acc[MH * 4 + mi][NH * 2 + ni] =
              mfma16(af[mi][k2], bf[ni][k2], acc[MH * 4 + mi][NH * 2 + ni]);
  };

  // ---- one K-step = 4 phases; stage stagger: P1->Blo(k+1), P2->Ahi(k+1),
  //      P3->Alo(k+2), P4->Bhi(k+2); vmcnt(4) at P4 leaves exactly those 2
  //      newest half-tiles in flight (verified: every region has >=1 barrier
  //      between its last LDS read completing and its overwrite issue). ----
  auto kstep = [&](int kst, f16* Ab, f16* Bb, f16* AbN, f16* BbN) {
    // P1: Q(Mlo,Nlo)
    loadA(Ab, 0); loadB(Bb, 0, blo);
    if (kst + 1 < KS) stageB(kst + 1, 0, BbN);
    __builtin_amdgcn_s_barrier();
    asm volatile("s_waitcnt lgkmcnt(0)" ::: "memory");
    __builtin_amdgcn_s_setprio(1);
    quadMM(0, 0, blo);
    __builtin_amdgcn_s_setprio(0);
    __builtin_amdgcn_s_barrier();
    // P2: Q(Mlo,Nhi)   (af lo reused)
    loadB(Bb, 1, bhi);
    if (kst + 1 < KS) stageA(kst + 1, 1, AbN);
    __builtin_amdgcn_s_barrier();
    asm volatile("s_waitcnt lgkmcnt(0)" ::: "memory");
    __builtin_amdgcn_s_setprio(1);
    quadMM(0, 1, bhi);
    __builtin_amdgcn_s_setprio(0);
    __builtin_amdgcn_s_barrier();
    // P3: Q(Mhi,Nhi)   (bhi reused)
    loadA(Ab, 1);
    if (kst + 2 < KS) stageA(kst + 2, 0, Ab);
    __builtin_amdgcn_s_barrier();
    asm volatile("s_waitcnt lgkmcnt(0)" ::: "memory");
    __builtin_amdgcn_s_setprio(1);
    quadMM(1, 1, bhi);
    __builtin_amdgcn_s_setprio(0);
    __builtin_amdgcn_s_barrier();
    // P4: Q(Mhi,Nlo)   (af hi + blo reused, no ds reads)
    if (kst + 2 < KS) stageB(kst + 2, 1, Bb);
    __builtin_amdgcn_s_barrier();
    asm volatile("s_waitcnt lgkmcnt(0)" ::: "memory");
    __builtin_amdgcn_s_setprio(1);
    quadMM(1, 0, blo);
    __builtin_amdgcn_s_setprio(0);
    if (kst + 2 < KS) asm volatile("s_waitcnt vmcnt(4)" ::: "memory");
    else              asm volatile("s_waitcnt vmcnt(0)" ::: "memory");
    __builtin_amdgcn_s_barrier();
  };

  // ---- prologue: prime pipeline to steady state (k=0 resident, k=1 Alo/Bhi
  //      in flight after vmcnt(4)) ----
  stageA(0, 0, A0);   // A-lo(0)
  stageB(0, 1, B0);   // B-hi(0)
  stageB(0, 0, B0);   // B-lo(0)
  stageA(0, 1, A0);   // A-hi(0)
  stageA(1, 0, A1);   // A-lo(1)
  stageB(1, 1, B1);   // B-hi(1)
  asm volatile("s_waitcnt vmcnt(4)" ::: "memory");
  __builtin_amdgcn_s_barrier();

#pragma unroll 1
  for (int k = 0; k < KS; k += 2) {
    kstep(k,     A0, B0, A1, B1);
    kstep(k + 1, A1, B1, A0, B0);
  }

  // ---- epilogue: bias + gate-mul + store (acc in regs, no LDS needed) ----
  const float* cbias = (ci == 0) ? cb0 : (ci == 1 ? cb1 : cb2);
#pragma unroll
  for (int mh = 0; mh < 2; ++mh)
#pragma unroll
    for (int mi = 0; mi < 4; ++mi)
#pragma unroll
      for (int nh = 0; nh < 2; ++nh)
#pragma unroll
        for (int ni = 0; ni < 2; ++ni) {
          int mg = mh * 128 + wr * 64 + mi * 16 + quad * 4;
          int lg = l0 + nh * 128 + wc * 32 + ni * 16 + l15;
          f32x4 a4 = acc[mh * 4 + mi][nh * 2 + ni];
#pragma unroll
          for (int r = 0; r < 4; ++r) {
            size_t a = ((size_t)(b * H_ + ci * 256 + mg + r)) * L_ + lg;
            float val = (a4[r] + cbias[mg + r]) * (float)gts[a];
            v[a] = (f16)val;
          }
        }
}

// ------- S4D: chunk end-states GEMM + fused carry scan -> Xin (f16). grid (2,768) -------
__global__ __launch_bounds__(256) void s1_states(const f16* __restrict__ v,
                                                 const f16* __restrict__ A1,
                                                 const float* __restrict__ WLc,
                                                 f16* __restrict__ Xin) {
  __shared__ f16 A1s[64 * 136];
  __shared__ f16 Vs[128 * 136];   // 34,816 B; aliased as Xls[128][68] f32 after MFMA
  const int h = blockIdx.y, cb = blockIdx.x;
  const int tid = threadIdx.x;
  {
    int row = tid >> 2, q = tid & 3;
    const f16x8* src = (const f16x8*)(A1 + ((size_t)h * 64 + row) * 128 + q * 32);
    f16x8* dst = (f16x8*)(&A1s[row * 136 + q * 32]);
    dst[0] = src[0]; dst[1] = src[1]; dst[2] = src[2]; dst[3] = src[3];
  }
  {
    int col = tid >> 1, half = tid & 1;
    int cg = cb * 128 + col, b = cg >> 5, c = cg & 31;
    const f16x8* src = (const f16x8*)(v + ((size_t)(b * H_ + h)) * L_ + c * 128 + half * 64);
    f16x8* dst = (f16x8*)(&Vs[col * 136 + half * 64]);
    dst[0] = src[0]; dst[1] = src[1]; dst[2] = src[2]; dst[3] = src[3];
    dst[4] = src[4]; dst[5] = src[5]; dst[6] = src[6]; dst[7] = src[7];
  }
  __syncthreads();
  const int wid = tid >> 6, lane = tid & 63, l15 = lane & 15, quad = lane >> 4;
  const int n0 = wid * 32;
  f32x4 acc[4][2];
#pragma unroll
  for (int i = 0; i < 4; ++i) { acc[i][0] = (f32x4){0,0,0,0}; acc[i][1] = (f32x4){0,0,0,0}; }
#pragma unroll
  for (int bk = 0; bk < 4; ++bk) {
    f16x8 af[4], bf[2];
#pragma unroll
    for (int mi = 0; mi < 4; ++mi)
      af[mi] = *(const f16x8*)(&A1s[(mi * 16 + l15) * 136 + bk * 32 + quad * 8]);
#pragma unroll
    for (int ni = 0; ni < 2; ++ni)
      bf[ni] = *(const f16x8*)(&Vs[(n0 + ni * 16 + l15) * 136 + bk * 32 + quad * 8]);
#pragma unroll
    for (int mi = 0; mi < 4; ++mi)
#pragma unroll
      for (int ni = 0; ni < 2; ++ni) acc[mi][ni] = mfma16(af[mi], bf[ni], acc[mi][ni]);
  }
  __syncthreads();                 // Vs reads complete; reuse as f32 scratch
  float* Xls = (float*)Vs;         // [col][68] f32 (exactly fits 34,816 B)
#pragma unroll
  for (int mi = 0; mi < 4; ++mi)
#pragma unroll
    for (int ni = 0; ni < 2; ++ni) {
      int col = n0 + ni * 16 + l15;
      *(f32x4*)(&Xls[col * 68 + mi * 16 + quad * 4]) = acc[mi][ni];
    }
  __syncthreads();
  if (tid < 128) {                 // one scan chain per (b4, n)
    int b4 = tid >> 5, n = tid & 31;
    int b = cb * 4 + b4;
    float Wr = WLc[(h * NST + n) * 2], Wi = WLc[(h * NST + n) * 2 + 1];
    float xr = 0.f, xi = 0.f;
    f16* xout = Xin + (((size_t)(b * H_ + h)) * NC) * 64 + 2 * n;
    for (int c = 0; c < NC; ++c) {
      float er = Xls[(b4 * 32 + c) * 68 + 2 * n];
      float ei = Xls[(b4 * 32 + c) * 68 + 2 * n + 1];
      f16x2 o; o[0] = (f16)xr; o[1] = (f16)xi;
      *(f16x2*)(xout + (size_t)c * 64) = o;    // state BEFORE chunk c
      float t = Wr * xr - Wi * xi + er;
      xi = Wr * xi + Wi * xr + ei; xr = t;
    }
  }
}

// y4 = Toeplitz(k_h) @ v_chunk + A2_h @ Xin + Dskip*v + res (f16 out). grid (4, 768)
__global__ __launch_bounds__(256) void s3_output(const f16* __restrict__ v,
                                                 const f16* __restrict__ A2g,
                                                 const f16* __restrict__ res,
                                                 const float* __restrict__ kT,
                                                 const f16* __restrict__ Xin,
                                                 const float* __restrict__ Dskip,
                                                 f16* __restrict__ y4) {
  __shared__ f16 Ts[128 * 136];   // phase2 aliases: A2s[128][72], Xs[64][72]
  __shared__ f16 Vs[64 * 136];
  __shared__ float kTs[128];
  f16* A2s = Ts;
  f16* Xs = Ts + 128 * 72;
  const int h = blockIdx.y, cb = blockIdx.x;
  const int tid = threadIdx.x;
  if (tid < 128) kTs[tid] = kT[h * 128 + tid];
  {
    int col = tid >> 2, q = tid & 3;
    int cg = cb * 64 + col, b = cg >> 5, c = cg & 31;
    const f16x8* src = (const f16x8*)(v + ((size_t)(b * H_ + h)) * L_ + c * 128 + q * 32);
    f16x8* dst = (f16x8*)(&Vs[col * 136 + q * 32]);
    dst[0] = src[0]; dst[1] = src[1]; dst[2] = src[2]; dst[3] = src[3];
  }
  __syncthreads();
  {  // build Toeplitz tile, vectorized: 8x ds_write_b128 per thread
    int tau = tid >> 1, h64 = (tid & 1) * 64;
#pragma unroll
    for (int jv = 0; jv < 8; ++jv) {
      int s0 = h64 + jv * 8;
      f16x8 w;
#pragma unroll
      for (int e = 0; e < 8; ++e) {
        int s = s0 + e;
        w[e] = (f16)((s <= tau) ? kTs[tau - s] : 0.f);
      }
      *(f16x8*)(&Ts[tau * 136 + s0]) = w;
    }
  }
  __syncthreads();
  const int wid = tid >> 6, lane = tid & 63, l15 = lane & 15, quad = lane >> 4;
  const int wm = (wid & 1) * 64, wn = (wid >> 1) * 32;
  f32x4 acc[4][2];
#pragma unroll
  for (int i = 0; i < 4; ++i) { acc[i][0] = (f32x4){0,0,0,0}; acc[i][1] = (f32x4){0,0,0,0}; }
#pragma unroll
  for (int bk = 0; bk < 4; ++bk) {
    f16x8 af[4], bf[2];
#pragma unroll
    for (int mi = 0; mi < 4; ++mi)
      af[mi] = *(const f16x8*)(&Ts[(wm + mi * 16 + l15) * 136 + bk * 32 + quad * 8]);
#pragma unroll
    for (int ni = 0; ni < 2; ++ni)
      bf[ni] = *(const f16x8*)(&Vs[(wn + ni * 16 + l15) * 136 + bk * 32 + quad * 8]);
#pragma unroll
    for (int mi = 0; mi < 4; ++mi)
#pragma unroll
      for (int ni = 0; ni < 2; ++ni) acc[mi][ni] = mfma16(af[mi], bf[ni], acc[mi][ni]);
  }
  __syncthreads();  // done with Ts; restage as A2s + Xs
  {
    int row = tid >> 1, half = tid & 1;
    const f16x8* src = (const f16x8*)(A2g + ((size_t)h * 128 + row) * 64 + half * 32);
    f16x8* dst = (f16x8*)(&A2s[row * 72 + half * 32]);
    dst[0] = src[0]; dst[1] = src[1]; dst[2] = src[2]; dst[3] = src[3];
  }
  {
    int col = tid >> 2, part = tid & 3;
    int cg = cb * 64 + col, b = cg >> 5, c = cg & 31;
    const f16x8* src = (const f16x8*)(Xin + (((size_t)(b * H_ + h)) * NC + c) * 64 + part * 16);
    f16x8* dst = (f16x8*)(&Xs[col * 72 + part * 16]);
    dst[0] = src[0]; dst[1] = src[1];
  }
  __syncthreads();
#pragma unroll
  for (int bk = 0; bk < 2; ++bk) {
    f16x8 af[4], bf[2];
#pragma unroll
    for (int mi = 0; mi < 4; ++mi)
      af[mi] = *(const f16x8*)(&A2s[(wm + mi * 16 + l15) * 72 + bk * 32 + quad * 8]);
#pragma unroll
    for (int ni = 0; ni < 2; ++ni)
      bf[ni] = *(const f16x8*)(&Xs[(wn + ni * 16 + l15) * 72 + bk * 32 + quad * 8]);
#pragma unroll
    for (int mi = 0; mi < 4; ++mi)
#pragma unroll
      for (int ni = 0; ni < 2; ++ni) acc[mi][ni] = mfma16(af[mi], bf[ni], acc[mi][ni]);
  }
  float Dh = Dskip[h];
#pragma unroll
  for (int mi = 0; mi < 4; ++mi)
#pragma unroll
    for (int ni = 0; ni < 2; ++ni) {
      int col = wn + ni * 16 + l15;
      int cg = cb * 64 + col, b = cg >> 5, c = cg & 31;
      int tau0 = wm + mi * 16 + quad * 4;
      size_t lbase = ((size_t)(b * H_ + h)) * L_ + c * 128 + tau0;
      const f16* rp = res + lbase;
      f16x4 o;
#pragma unroll
      for (int r = 0; r < 4; ++r)
        o[r] = (f16)(acc[mi][ni][r] + Dh * (float)Vs[col * 136 + tau0 + r] + (float)rp[r]);
      *(f16x4*)(y4 + lbase) = o;
    }
}

// transpose + LayerNorm over H=768.  grid (64 l-tiles, 8 b); y4 is f16 [b,h,l]
__global__ __launch_bounds__(256) void layernorm_t(const f16* __restrict__ y4,
                                                   const float* __restrict__ gamma,
                                                   const float* __restrict__ beta,
                                                   float* __restrict__ out) {
  __shared__ f16 Ys[768 * 72];
  __shared__ float psum[256], psq[256], mu[64], rs[64];
  const int b = blockIdx.y, l0 = blockIdx.x * 64;
  const int tid = threadIdx.x;
  {
    int r8 = tid >> 3, c = tid & 7;   // 8 lanes x 16 B per 128 B row; 32 rows/iter
    for (int it = 0; it < 24; ++it) {
      int hh = it * 32 + r8;
      f16x8 x = *(const f16x8*)(y4 + ((size_t)(b * H_ + hh)) * L_ + l0 + c * 8);
      *(f16x8*)(&Ys[hh * 72 + c * 8]) = x;
    }
  }
  __syncthreads();
  {
    int l = tid & 63, hg = tid >> 6;
    float s = 0.f, s2 = 0.f;
    for (int k = 0; k < 192; ++k) {
      float val = (float)Ys[(hg * 192 + k) * 72 + l];
      s += val; s2 += val * val;
    }
    psum[hg * 64 + l] = s; psq[hg * 64 + l] = s2;
  }
  __syncthreads();
  if (tid < 64) {
    float S = 0.f, S2 = 0.f;
    for (int g = 0; g < 4; ++g) { S += psum[g * 64 + tid]; S2 += psq[g * 64 + tid]; }
    float m = S / 768.f;
    float var = S2 / 768.f - m * m;
    mu[tid] = m; rs[tid] = rsqrtf(var + 1e-5f);
  }
  __syncthreads();
  float g0 = gamma[tid], g1 = gamma[256 + tid], g2 = gamma[512 + tid];
  float be0 = beta[tid], be1 = beta[256 + tid], be2 = beta[512 + tid];
  for (int lv = 0; lv < 8; ++lv) {
    f16x8 y0 = *(const f16x8*)(&Ys[(size_t)tid * 72 + lv * 8]);
    f16x8 y1 = *(const f16x8*)(&Ys[(size_t)(256 + tid) * 72 + lv * 8]);
    f16x8 y2 = *(const f16x8*)(&Ys[(size_t)(512 + tid) * 72 + lv * 8]);
#pragma unroll
    for (int e = 0; e < 8; ++e) {
      int ll = lv * 8 + e;
      float m = mu[ll], r = rs[ll];
      size_t ob = ((size_t)b * L_ + l0 + ll) * H_;
      out[ob + tid]       = ((float)y0[e] - m) * r * g0 + be0;
      out[ob + 256 + tid] = ((float)y1[e] - m) * r * g1 + be1;
      out[ob + 512 + tid] = ((float)y2[e] - m) * r * g2 + be2;
    }
  }
}

// ---------------- launch ----------------
extern "C" void kernel_launch(void* const* d_in, const int* in_sizes, int n_in,
                              void* d_out, int out_size, void* d_ws, size_t ws_size,
                              hipStream_t stream) {
  const float* x      = (const float*)d_in[0];
  const float* cw0    = (const float*)d_in[1];
  const float* cb0    = (const float*)d_in[2];
  const float* cw1    = (const float*)d_in[3];
  const float* cb1    = (const float*)d_in[4];
  const float* cw2    = (const float*)d_in[5];
  const float* cb2    = (const float*)d_in[6];
  const float* gate_w = (const float*)d_in[7];
  const float* gate_b = (const float*)d_in[8];
  const float* res_w  = (const float*)d_in[9];
  const float* res_b  = (const float*)d_in[10];
  const float* log_dt = (const float*)d_in[11];
  const float* A_re   = (const float*)d_in[12];
  const float* A_im   = (const float*)d_in[13];
  const float* C_re   = (const float*)d_in[14];
  const float* C_im   = (const float*)d_in[15];
  const float* Dskip  = (const float*)d_in[16];
  const float* ln_g   = (const float*)d_in[17];
  const float* ln_b   = (const float*)d_in[18];
  float* out = (float*)d_out;

  char* ws = (char*)d_ws;
  f16*   xh   = (f16*)(ws + 0);            // 16,777,216
  f16*   Ac   = (f16*)(ws + 16777216);     //  3,276,800
  f16*   Ag   = (f16*)(ws + 20054016);     //    786,432 (gate_w ++ res_w)
  f16*   zbuf = (f16*)(ws + 20840448);     //      1,024
  f16*   vb   = (f16*)(ws + 20841472);     // 50,331,648
  f16*   resb = (f16*)(ws + 71173120);     // 50,331,648
  f16*   gts  = (f16*)(ws + 121504768);    // 50,331,648
  f16*   A1   = (f16*)(ws + 171836416);    // 12,582,912
  f16*   A2   = (f16*)(ws + 184419328);    // 12,582,912
  float* kT   = (float*)(ws + 197002240);  //    393,216
  float* WLc  = (float*)(ws + 197395456);  //    196,608
  f16*   Xin  = (f16*)(ws + 197592064);    // 25,165,824
  f16*   y4   = (f16*)(ws + 222757888);    // 50,331,648   (total ~273 MB)

  prep_all<<<14977, 256, 0, stream>>>(x, gate_w, res_w, cw0, cw1, cw2,
                                      xh, Ag, (float*)zbuf, Ac);
  s4_all<<<480, 256, 0, stream>>>(log_dt, A_re, A_im, C_re, C_im, A1, A2, WLc, kT);

  gemm_gr<<<dim3(256, 12), 256, 0, stream>>>(xh, Ag, gate_b, res_b, gts, resb);
  gemm_conv8<<<dim3(128, 3), 512, 0, stream>>>(xh, Ac, cb0, cb1, cb2, gts, zbuf, vb);

  s1_states<<<dim3(2, 768), 256, 0, stream>>>(vb, A1, WLc, Xin);
  s3_output<<<dim3(4, 768), 256, 0, stream>>>(vb, A2, resb, kT, Xin, Dskip, y4);

  layernorm_t<<<dim3(64, 8), 256, 0, stream>>>(y4, ln_g, ln_b, out);
}

// Round 2
// 453.610 us; speedup vs baseline: 1.0116x; 1.0116x over previous
//
#include <hip/hip_runtime.h>
#include <cstdint>
#include <cstddef>

// StripedHyena layer on MI355X.
// R7: gemm_conv restructured as B-RESIDENT conv-GEMM. R6's neutral result
// (5240 cyc/K-step vs 2483 MFMA-bound) was diagnosed as staging-THROUGHPUT
// bound: 128 KiB/K-step from L2 (~2340 cyc) serialized with MFMA. Fix: loop
// order (jc outer, tap inner) keeps a 320x64 B-slab resident in LDS per
// j-block (staged once, 24x less B traffic for taps=15); only A (32 KiB/step)
// is restaged, triple-buffered with counted vmcnt(4). Per-step staging drops
// 4x; staging now fits under the MFMA shadow.

#define B_ 8
#define L_ 4096
#define D_ 256
#define H_ 768
#define NST 32
#define LC 128
#define NC 32

typedef _Float16 f16;
typedef _Float16 f16x8 __attribute__((ext_vector_type(8)));
typedef _Float16 f16x4 __attribute__((ext_vector_type(4)));
typedef _Float16 f16x2 __attribute__((ext_vector_type(2)));
typedef float f32x4 __attribute__((ext_vector_type(4)));

__device__ __forceinline__ f32x4 mfma16(f16x8 a, f16x8 b, f32x4 c) {
  return __builtin_amdgcn_mfma_f32_16x16x32_f16(a, b, c, 0, 0, 0);
}

#define GLDS16(g, l)                                                              \
  __builtin_amdgcn_global_load_lds((const __attribute__((address_space(1))) void*)(g), \
                                   (__attribute__((address_space(3))) void*)(l), 16, 0, 0)

// ---------------- fused prep: casts + zero buffer + conv A-matrix ----------------
__global__ __launch_bounds__(256) void prep_all(
    const float* __restrict__ x, const float* __restrict__ gate_w,
    const float* __restrict__ res_w,
    const float* __restrict__ w0, const float* __restrict__ w1, const float* __restrict__ w2,
    f16* __restrict__ xh, f16* __restrict__ Ag, float* __restrict__ zbuf,
    f16* __restrict__ A) {
  int bid = blockIdx.x, tid = threadIdx.x;
  if (bid < 8192) {            // cast x -> xh
    int i = (bid * 256 + tid) * 4;
    float4 v = *(const float4*)(x + i);
    xh[i+0]=(f16)v.x; xh[i+1]=(f16)v.y; xh[i+2]=(f16)v.z; xh[i+3]=(f16)v.w;
  } else if (bid < 8384) {     // cast gate_w
    int i = ((bid - 8192) * 256 + tid) * 4;
    float4 v = *(const float4*)(gate_w + i);
    Ag[i+0]=(f16)v.x; Ag[i+1]=(f16)v.y; Ag[i+2]=(f16)v.z; Ag[i+3]=(f16)v.w;
  } else if (bid < 8576) {     // cast res_w
    int i = ((bid - 8384) * 256 + tid) * 4;
    float4 v = *(const float4*)(res_w + i);
    f16* d = Ag + 768 * 256;
    d[i+0]=(f16)v.x; d[i+1]=(f16)v.y; d[i+2]=(f16)v.z; d[i+3]=(f16)v.w;
  } else if (bid == 8576) {    // zero buffer for OOB dilation rows
    zbuf[tid] = 0.f;
  } else {                     // conv weights -> A[o][t*256+j] layout
    int idx = (bid - 8577) * 256 + tid;   // exactly 1,638,400
    const int n0 = 256 * 256 * 3, n1 = 256 * 256 * 7;
    const float* w; int K, base;
    if (idx < n0) { w = w0; K = 3; base = 0; }
    else if (idx < n0 + n1) { idx -= n0; w = w1; K = 7; base = 256 * 768; }
    else { idx -= n0 + n1; w = w2; K = 15; base = 256 * 768 + 256 * 1792; }
    int o = idx / (256 * K); int r = idx - o * (256 * K); int j = r / K; int t = r - j * K;
    A[base + o * (256 * K) + t * 256 + j] = (f16)w[idx];
  }
}

// ---------------- fused S4D parameter build ----------------
__global__ __launch_bounds__(256) void s4_all(const float* __restrict__ log_dt,
                                              const float* __restrict__ A_re,
                                              const float* __restrict__ A_im,
                                              const float* __restrict__ C_re,
                                              const float* __restrict__ C_im,
                                              f16* __restrict__ A1, f16* __restrict__ A2,
                                              float* __restrict__ WLc,
                                              float* __restrict__ kT) {
  int bid = blockIdx.x, tid = threadIdx.x;
  if (bid < 96) {
    int idx = bid * 256 + tid;  // h*32+n
    int h = idx >> 5, n = idx & 31;
    float dt = expf(log_dt[h]);
    float Ar = A_re[idx], Ai = A_im[idx];
    float ar = dt * Ar, ai = dt * Ai;
    float e = expf(ar), sn, cs; sincosf(ai, &sn, &cs);
    float wr = e * cs, wi = e * sn;                 // w = exp(dt*A)
    float den = Ar * Ar + Ai * Ai;
    float Er = wr - 1.f, Ei = wi;
    float Cr = C_re[idx], Ci = C_im[idx];
    float nr = Cr * Er - Ci * Ei, ni = Cr * Ei + Ci * Er;
    float Cdr = (nr * Ar + ni * Ai) / den;          // C_disc = C*(w-1)/A
    float Cdi = (ni * Ar - nr * Ai) / den;
    f16* A1r = A1 + ((size_t)h * 64 + 2 * n) * LC;
    f16* A1i = A1 + ((size_t)h * 64 + 2 * n + 1) * LC;
    float pr = 1.f, pi = 0.f;
    for (int j = 0; j < LC; ++j) {
      A1r[LC - 1 - j] = (f16)pr; A1i[LC - 1 - j] = (f16)pi;
      float t0 = pr * wr - pi * wi; pi = pr * wi + pi * wr; pr = t0;
    }
    WLc[idx * 2] = pr; WLc[idx * 2 + 1] = pi;       // w^128
    float qr = wr, qi = wi;
    for (int t = 0; t < LC; ++t) {
      A2[((size_t)h * LC + t) * 64 + 2 * n]     = (f16)(2.f * (Cdr * qr - Cdi * qi));
      A2[((size_t)h * LC + t) * 64 + 2 * n + 1] = (f16)(-2.f * (Cdr * qi + Cdi * qr));
      float t0 = qr * wr - qi * wi; qi = qr * wi + qi * wr; qr = t0;
    }
  } else {
    int idx = (bid - 96) * 256 + tid;  // h*128+j
    int h = idx >> 7, j = idx & 127;
    float dt = expf(log_dt[h]);
    float acc = 0.f;
    for (int n = 0; n < NST; ++n) {
      float Ar = A_re[h * 32 + n], Ai = A_im[h * 32 + n];
      float ar = dt * Ar, ai = dt * Ai;
      float e1 = expf(ar), s1, c1; sincosf(ai, &s1, &c1);
      float wr = e1 * c1, wi = e1 * s1;
      float den = Ar * Ar + Ai * Ai;
      float Er = wr - 1.f, Ei = wi;
      float Cr = C_re[h * 32 + n], Ci = C_im[h * 32 + n];
      float nr = Cr * Er - Ci * Ei, ni = Cr * Ei + Ci * Er;
      float Cdr = (nr * Ar + ni * Ai) / den, Cdi = (ni * Ar - nr * Ai) / den;
      float ej = expf(ar * (float)j), sj, cj; sincosf(ai * (float)j, &sj, &cj);
      acc += 2.f * (Cdr * (ej * cj) - Cdi * (ej * sj));
    }
    kT[idx] = acc;
  }
}

// -------- GEMM 1: gate + res projections (K=256). grid (256, 12) --------
__global__ __launch_bounds__(256) void gemm_gr(
    const f16* __restrict__ xh, const f16* __restrict__ Agr,
    const float* __restrict__ gate_b, const float* __restrict__ res_b,
    f16* __restrict__ gts, f16* __restrict__ res) {
  __shared__ f16 As[128 * 64];
  __shared__ f16 Bs[128 * 64];
  const int mt = blockIdx.y, nt = blockIdx.x;
  const int b = nt >> 5, l0 = (nt & 31) * 128;
  const bool isg = mt < 6;
  const int hbase = (isg ? mt : mt - 6) * 128;
  const f16* Abase = Agr + (size_t)((isg ? 0 : 768) + hbase) * 256;
  const int tid = threadIdx.x;
  const int wid = tid >> 6, lane = tid & 63, l15 = lane & 15, quad = lane >> 4;
  const int wm = (wid & 1) * 64, wn = (wid >> 1) * 64;
  const int srow = (wid << 5) + (lane >> 3);
  const int sperm = ((lane & 7) ^ (lane >> 3)) << 3;
  char* AsL = (char*)As + (wid << 12);
  char* BsL = (char*)Bs + (wid << 12);
  const f16* xrow = xh + (((size_t)b * L_) << 8);

  f32x4 acc[4][4];
#pragma unroll
  for (int i = 0; i < 4; ++i)
#pragma unroll
    for (int j = 0; j < 4; ++j) acc[i][j] = (f32x4){0.f, 0.f, 0.f, 0.f};

  for (int kc = 0; kc < 4; ++kc) {
#pragma unroll
    for (int j = 0; j < 4; ++j) {
      int row = srow + j * 8;
      GLDS16(Abase + (size_t)row * 256 + kc * 64 + sperm, AsL + (j << 10));
      GLDS16(xrow + ((size_t)(l0 + row) << 8) + kc * 64 + sperm, BsL + (j << 10));
    }
    __syncthreads();
#pragma unroll
    for (int k2 = 0; k2 < 2; ++k2) {
      f16x8 af[4], bf[4];
#pragma unroll
      for (int mi = 0; mi < 4; ++mi) {
        int r = wm + mi * 16 + l15;
        af[mi] = *(const f16x8*)(&As[r * 64 + (((k2 * 4 + quad) ^ (r & 7)) << 3)]);
      }
#pragma unroll
      for (int ni = 0; ni < 4; ++ni) {
        int r = wn + ni * 16 + l15;
        bf[ni] = *(const f16x8*)(&Bs[r * 64 + (((k2 * 4 + quad) ^ (r & 7)) << 3)]);
      }
#pragma unroll
      for (int mi = 0; mi < 4; ++mi)
#pragma unroll
        for (int ni = 0; ni < 4; ++ni) acc[mi][ni] = mfma16(af[mi], bf[ni], acc[mi][ni]);
    }
    __syncthreads();
  }

  if (isg) {
#pragma unroll
    for (int mi = 0; mi < 4; ++mi)
#pragma unroll
      for (int ni = 0; ni < 4; ++ni) {
        int hg = hbase + wm + mi * 16 + quad * 4;
        int lg = l0 + wn + ni * 16 + l15;
#pragma unroll
        for (int r = 0; r < 4; ++r) {
          float val = acc[mi][ni][r] + gate_b[hg + r];
          gts[((size_t)(b * H_ + hg + r)) * L_ + lg] = (f16)(1.f / (1.f + expf(-val)));
        }
      }
  } else {
#pragma unroll
    for (int mi = 0; mi < 4; ++mi)
#pragma unroll
      for (int ni = 0; ni < 4; ++ni) {
        int hg = hbase + wm + mi * 16 + quad * 4;
        int lg = l0 + wn + ni * 16 + l15;
#pragma unroll
        for (int r = 0; r < 4; ++r)
          res[((size_t)(b * H_ + hg + r)) * L_ + lg] = (f16)(acc[mi][ni][r] + res_b[hg + r]);
      }
  }
}

// -------- GEMM 2: dilated convs, 256^2 tile, B-RESIDENT. grid (128, 3).
// jc outer (4 x 64-channel blocks), tap inner. B slab [320][64] staged once
// per jc (zero-padded OOB); taps read it at row shift 32+boff(t). A tiles
// (256x64, 32 KiB) triple-buffered, prefetched 2 steps ahead, counted
// vmcnt(4). 512 thr, 8 waves (2Mx4N), 136 KiB LDS, 1 block/CU. --------
__global__ __launch_bounds__(512, 2) void gemm_conv8(
    const f16* __restrict__ xh, const f16* __restrict__ Aconv,
    const float* __restrict__ cb0, const float* __restrict__ cb1, const float* __restrict__ cb2,
    const f16* __restrict__ gts, const f16* __restrict__ zbuf,
    f16* __restrict__ v) {
  __shared__ f16 lds[69632];     // 3 A-bufs (3*16384) + B slab (320*64) = 139,264 B
  f16* Bs = lds + 49152;

  const int nt = blockIdx.x;
  const int b = nt >> 4, l0 = (nt & 15) * 256;
  const int ci = 2 - blockIdx.y;           // heavy (taps=15) dispatched first
  const int tid = threadIdx.x;
  const int wid = tid >> 6, lane = tid & 63, l15 = lane & 15, quad = lane >> 4;
  const int wr = wid >> 2, wc = wid & 3;   // 2 (M) x 4 (N) wave grid
  const int rq = tid >> 3;                 // stage row-within-round (0..63)
  const int cswz = ((tid & 7) ^ ((tid >> 3) & 7)) << 3;  // stage src swizzle (f16)
  const f16* xrow = xh + (((size_t)b * L_) << 8);

  const f16* Acb; int Krow, taps, dil;
  if (ci == 0)      { Acb = Aconv;                          Krow = 768;  taps = 3;  dil = 1; }
  else if (ci == 1) { Acb = Aconv + 256 * 768;              Krow = 1792; taps = 7;  dil = 2; }
  else              { Acb = Aconv + 256 * 768 + 256 * 1792; Krow = 3840; taps = 15; dil = 4; }
  const int S = taps * 4;                  // total K-steps (jc x tap)
  const int half = (taps - 1) / 2;

  f32x4 acc[8][4];
#pragma unroll
  for (int i = 0; i < 8; ++i)
#pragma unroll
    for (int j = 0; j < 4; ++j) acc[i][j] = (f32x4){0.f, 0.f, 0.f, 0.f};
  f16x8 af[4][2], blo[2][2], bhi[2][2];

  // ---- stage B slab for j-block jc: 320 rows x 64 cols, 5 rounds ----
  auto stageB = [&](int jc) {
#pragma unroll
    for (int q = 0; q < 5; ++q) {
      int r = q * 64 + rq;                 // physical row 0..319
      int gl = l0 - 32 + r;
      const f16* src = (gl < 0 || gl >= L_) ? (zbuf + cswz)
                       : xrow + ((size_t)gl << 8) + jc * 64 + cswz;
      GLDS16(src, Bs + q * 4096 + wid * 512);
    }
  };
  // ---- stage 2 rounds of an A tile (t2, jc2) into buf ----
  auto stageA2 = [&](int t2, int jc2, f16* buf, int q0) {
#pragma unroll
    for (int q = q0; q < q0 + 2; ++q) {
      const f16* src = Acb + (size_t)(q * 64 + rq) * Krow + t2 * 256 + jc2 * 64 + cswz;
      GLDS16(src, buf + q * 4096 + wid * 512);
    }
  };
  auto loadA = [&](const f16* Ab, int MH) {
#pragma unroll
    for (int mi = 0; mi < 4; ++mi) {
      int r = MH * 128 + wr * 64 + mi * 16 + l15;
#pragma unroll
      for (int k2 = 0; k2 < 2; ++k2)
        af[mi][k2] = *(const f16x8*)(Ab + r * 64 + (((k2 * 4 + quad) ^ (r & 7)) << 3));
    }
  };
  auto loadB = [&](int NH, int shift, f16x8 (&bf)[2][2]) {
#pragma unroll
    for (int ni = 0; ni < 2; ++ni) {
      int r = shift + NH * 128 + wc * 32 + ni * 16 + l15;   // physical B row
#pragma unroll
      for (int k2 = 0; k2 < 2; ++k2)
        bf[ni][k2] = *(const f16x8*)(Bs + r * 64 + (((k2 * 4 + quad) ^ (r & 7)) << 3));
    }
  };
  auto quadMM = [&](int MH, int NH, f16x8 (&bf)[2][2]) {
#pragma unroll
    for (int k2 = 0; k2 < 2; ++k2)
#pragma unroll
      for (int mi = 0; mi < 4; ++mi)
#pragma unroll
        for (int ni = 0; ni < 2; ++ni)
          acc[MH * 4 + mi][NH * 2 + ni] =
              mfma16(af[mi][k2], bf[ni][k2], acc[MH * 4 + mi][NH * 2 + ni]);
  };

  // ---- prologue: B(jc=0) + A(0) + A(1), full drain ----
  stageB(0);
  stageA2(0, 0, lds, 0);           stageA2(0, 0, lds, 2);
  stageA2(1, 0, lds + 16384, 0);   stageA2(1, 0, lds + 16384, 2);
  asm volatile("s_waitcnt vmcnt(0)" ::: "memory");
  __builtin_amdgcn_s_barrier();

  int s = 0, ca = 0;                       // ca = (s % 3) buffer index
#pragma unroll 1
  for (int jc = 0; jc < 4; ++jc) {
    if (jc > 0) {                          // restage B slab (reads of old slab done)
      stageB(jc);
      asm volatile("s_waitcnt vmcnt(0)" ::: "memory");
      __builtin_amdgcn_s_barrier();
    }
#pragma unroll 1
    for (int t = 0; t < taps; ++t, ++s) {
      const int shift = 32 + (t - half) * dil;
      f16* Acur = lds + ca * 16384;
      int pa = ca - 1; if (pa < 0) pa = 2; // (s+2) % 3
      f16* Apre = lds + pa * 16384;
      int t2 = t + 2, jc2 = jc;
      if (t2 >= taps) { t2 -= taps; ++jc2; }
      const bool pf = (jc2 < 4);
      // P1: Q(Mlo,Nlo)
      loadA(Acur, 0); loadB(0, shift, blo);
      if (pf) stageA2(t2, jc2, Apre, 0);
      __builtin_amdgcn_s_barrier();
      asm volatile("s_waitcnt lgkmcnt(0)" ::: "memory");
      __builtin_amdgcn_s_setprio(1);
      quadMM(0, 0, blo);
      __builtin_amdgcn_s_setprio(0);
      __builtin_amdgcn_s_barrier();
      // P2: Q(Mlo,Nhi)   (af lo reused)
      loadB(1, shift, bhi);
      if (pf) stageA2(t2, jc2, Apre, 2);
      __builtin_amdgcn_s_barrier();
      asm volatile("s_waitcnt lgkmcnt(0)" ::: "memory");
      __builtin_amdgcn_s_setprio(1);
      quadMM(0, 1, bhi);
      __builtin_amdgcn_s_setprio(0);
      __builtin_amdgcn_s_barrier();
      // P3: Q(Mhi,Nhi)   (bhi reused)
      loadA(Acur, 1);
      __builtin_amdgcn_s_barrier();
      asm volatile("s_waitcnt lgkmcnt(0)" ::: "memory");
      __builtin_amdgcn_s_setprio(1);
      quadMM(1, 1, bhi);
      __builtin_amdgcn_s_setprio(0);
      __builtin_amdgcn_s_barrier();
      // P4: Q(Mhi,Nlo)   (af hi + blo reused, no ds ops)
      __builtin_amdgcn_s_setprio(1);
      quadMM(1, 0, blo);
      __builtin_amdgcn_s_setprio(0);
      if (pf) asm volatile("s_waitcnt vmcnt(4)" ::: "memory");  // A(s+1) drained, A(s+2) in flight
      else    asm volatile("s_waitcnt vmcnt(0)" ::: "memory");
      __builtin_amdgcn_s_barrier();
      ca = (ca == 2) ? 0 : ca + 1;
    }
  }

  // ---- epilogue: bias + gate-mul + store (acc in regs) ----
  const float* cbias = (ci == 0) ? cb0 : (ci == 1 ? cb1 : cb2);
#pragma unroll
  for (int mh = 0; mh < 2; ++mh)
#pragma unroll
    for (int mi = 0; mi < 4; ++mi)
#pragma unroll
      for (int nh = 0; nh < 2; ++nh)
#pragma unroll
        for (int ni = 0; ni < 2; ++ni) {
          int mg = mh * 128 + wr * 64 + mi * 16 + quad * 4;
          int lg = l0 + nh * 128 + wc * 32 + ni * 16 + l15;
          f32x4 a4 = acc[mh * 4 + mi][nh * 2 + ni];
#pragma unroll
          for (int r = 0; r < 4; ++r) {
            size_t a = ((size_t)(b * H_ + ci * 256 + mg + r)) * L_ + lg;
            float val = (a4[r] + cbias[mg + r]) * (float)gts[a];
            v[a] = (f16)val;
          }
        }
}

// ------- S4D: chunk end-states GEMM + fused carry scan -> Xin (f16). grid (2,768) -------
__global__ __launch_bounds__(256) void s1_states(const f16* __restrict__ v,
                                                 const f16* __restrict__ A1,
                                                 const float* __restrict__ WLc,
                                                 f16* __restrict__ Xin) {
  __shared__ f16 A1s[64 * 136];
  __shared__ f16 Vs[128 * 136];   // 34,816 B; aliased as Xls[128][68] f32 after MFMA
  const int h = blockIdx.y, cb = blockIdx.x;
  const int tid = threadIdx.x;
  {
    int row = tid >> 2, q = tid & 3;
    const f16x8* src = (const f16x8*)(A1 + ((size_t)h * 64 + row) * 128 + q * 32);
    f16x8* dst = (f16x8*)(&A1s[row * 136 + q * 32]);
    dst[0] = src[0]; dst[1] = src[1]; dst[2] = src[2]; dst[3] = src[3];
  }
  {
    int col = tid >> 1, half = tid & 1;
    int cg = cb * 128 + col, b = cg >> 5, c = cg & 31;
    const f16x8* src = (const f16x8*)(v + ((size_t)(b * H_ + h)) * L_ + c * 128 + half * 64);
    f16x8* dst = (f16x8*)(&Vs[col * 136 + half * 64]);
    dst[0] = src[0]; dst[1] = src[1]; dst[2] = src[2]; dst[3] = src[3];
    dst[4] = src[4]; dst[5] = src[5]; dst[6] = src[6]; dst[7] = src[7];
  }
  __syncthreads();
  const int wid = tid >> 6, lane = tid & 63, l15 = lane & 15, quad = lane >> 4;
  const int n0 = wid * 32;
  f32x4 acc[4][2];
#pragma unroll
  for (int i = 0; i < 4; ++i) { acc[i][0] = (f32x4){0,0,0,0}; acc[i][1] = (f32x4){0,0,0,0}; }
#pragma unroll
  for (int bk = 0; bk < 4; ++bk) {
    f16x8 af[4], bf[2];
#pragma unroll
    for (int mi = 0; mi < 4; ++mi)
      af[mi] = *(const f16x8*)(&A1s[(mi * 16 + l15) * 136 + bk * 32 + quad * 8]);
#pragma unroll
    for (int ni = 0; ni < 2; ++ni)
      bf[ni] = *(const f16x8*)(&Vs[(n0 + ni * 16 + l15) * 136 + bk * 32 + quad * 8]);
#pragma unroll
    for (int mi = 0; mi < 4; ++mi)
#pragma unroll
      for (int ni = 0; ni < 2; ++ni) acc[mi][ni] = mfma16(af[mi], bf[ni], acc[mi][ni]);
  }
  __syncthreads();                 // Vs reads complete; reuse as f32 scratch
  float* Xls = (float*)Vs;         // [col][68] f32 (exactly fits 34,816 B)
#pragma unroll
  for (int mi = 0; mi < 4; ++mi)
#pragma unroll
    for (int ni = 0; ni < 2; ++ni) {
      int col = n0 + ni * 16 + l15;
      *(f32x4*)(&Xls[col * 68 + mi * 16 + quad * 4]) = acc[mi][ni];
    }
  __syncthreads();
  if (tid < 128) {                 // one scan chain per (b4, n)
    int b4 = tid >> 5, n = tid & 31;
    int b = cb * 4 + b4;
    float Wr = WLc[(h * NST + n) * 2], Wi = WLc[(h * NST + n) * 2 + 1];
    float xr = 0.f, xi = 0.f;
    f16* xout = Xin + (((size_t)(b * H_ + h)) * NC) * 64 + 2 * n;
    for (int c = 0; c < NC; ++c) {
      float er = Xls[(b4 * 32 + c) * 68 + 2 * n];
      float ei = Xls[(b4 * 32 + c) * 68 + 2 * n + 1];
      f16x2 o; o[0] = (f16)xr; o[1] = (f16)xi;
      *(f16x2*)(xout + (size_t)c * 64) = o;    // state BEFORE chunk c
      float t = Wr * xr - Wi * xi + er;
      xi = Wr * xi + Wi * xr + ei; xr = t;
    }
  }
}

// y4 = Toeplitz(k_h) @ v_chunk + A2_h @ Xin + Dskip*v + res (f16 out). grid (4, 768)
__global__ __launch_bounds__(256) void s3_output(const f16* __restrict__ v,
                                                 const f16* __restrict__ A2g,
                                                 const f16* __restrict__ res,
                                                 const float* __restrict__ kT,
                                                 const f16* __restrict__ Xin,
                                                 const float* __restrict__ Dskip,
                                                 f16* __restrict__ y4) {
  __shared__ f16 Ts[128 * 136];   // phase2 aliases: A2s[128][72], Xs[64][72]
  __shared__ f16 Vs[64 * 136];
  __shared__ float kTs[128];
  f16* A2s = Ts;
  f16* Xs = Ts + 128 * 72;
  const int h = blockIdx.y, cb = blockIdx.x;
  const int tid = threadIdx.x;
  if (tid < 128) kTs[tid] = kT[h * 128 + tid];
  {
    int col = tid >> 2, q = tid & 3;
    int cg = cb * 64 + col, b = cg >> 5, c = cg & 31;
    const f16x8* src = (const f16x8*)(v + ((size_t)(b * H_ + h)) * L_ + c * 128 + q * 32);
    f16x8* dst = (f16x8*)(&Vs[col * 136 + q * 32]);
    dst[0] = src[0]; dst[1] = src[1]; dst[2] = src[2]; dst[3] = src[3];
  }
  __syncthreads();
  {  // build Toeplitz tile, vectorized: 8x ds_write_b128 per thread
    int tau = tid >> 1, h64 = (tid & 1) * 64;
#pragma unroll
    for (int jv = 0; jv < 8; ++jv) {
      int s0 = h64 + jv * 8;
      f16x8 w;
#pragma unroll
      for (int e = 0; e < 8; ++e) {
        int s = s0 + e;
        w[e] = (f16)((s <= tau) ? kTs[tau - s] : 0.f);
      }
      *(f16x8*)(&Ts[tau * 136 + s0]) = w;
    }
  }
  __syncthreads();
  const int wid = tid >> 6, lane = tid & 63, l15 = lane & 15, quad = lane >> 4;
  const int wm = (wid & 1) * 64, wn = (wid >> 1) * 32;
  f32x4 acc[4][2];
#pragma unroll
  for (int i = 0; i < 4; ++i) { acc[i][0] = (f32x4){0,0,0,0}; acc[i][1] = (f32x4){0,0,0,0}; }
#pragma unroll
  for (int bk = 0; bk < 4; ++bk) {
    f16x8 af[4], bf[2];
#pragma unroll
    for (int mi = 0; mi < 4; ++mi)
      af[mi] = *(const f16x8*)(&Ts[(wm + mi * 16 + l15) * 136 + bk * 32 + quad * 8]);
#pragma unroll
    for (int ni = 0; ni < 2; ++ni)
      bf[ni] = *(const f16x8*)(&Vs[(wn + ni * 16 + l15) * 136 + bk * 32 + quad * 8]);
#pragma unroll
    for (int mi = 0; mi < 4; ++mi)
#pragma unroll
      for (int ni = 0; ni < 2; ++ni) acc[mi][ni] = mfma16(af[mi], bf[ni], acc[mi][ni]);
  }
  __syncthreads();  // done with Ts; restage as A2s + Xs
  {
    int row = tid >> 1, half = tid & 1;
    const f16x8* src = (const f16x8*)(A2g + ((size_t)h * 128 + row) * 64 + half * 32);
    f16x8* dst = (f16x8*)(&A2s[row * 72 + half * 32]);
    dst[0] = src[0]; dst[1] = src[1]; dst[2] = src[2]; dst[3] = src[3];
  }
  {
    int col = tid >> 2, part = tid & 3;
    int cg = cb * 64 + col, b = cg >> 5, c = cg & 31;
    const f16x8* src = (const f16x8*)(Xin + (((size_t)(b * H_ + h)) * NC + c) * 64 + part * 16);
    f16x8* dst = (f16x8*)(&Xs[col * 72 + part * 16]);
    dst[0] = src[0]; dst[1] = src[1];
  }
  __syncthreads();
#pragma unroll
  for (int bk = 0; bk < 2; ++bk) {
    f16x8 af[4], bf[2];
#pragma unroll
    for (int mi = 0; mi < 4; ++mi)
      af[mi] = *(const f16x8*)(&A2s[(wm + mi * 16 + l15) * 72 + bk * 32 + quad * 8]);
#pragma unroll
    for (int ni = 0; ni < 2; ++ni)
      bf[ni] = *(const f16x8*)(&Xs[(wn + ni * 16 + l15) * 72 + bk * 32 + quad * 8]);
#pragma unroll
    for (int mi = 0; mi < 4; ++mi)
#pragma unroll
      for (int ni = 0; ni < 2; ++ni) acc[mi][ni] = mfma16(af[mi], bf[ni], acc[mi][ni]);
  }
  float Dh = Dskip[h];
#pragma unroll
  for (int mi = 0; mi < 4; ++mi)
#pragma unroll
    for (int ni = 0; ni < 2; ++ni) {
      int col = wn + ni * 16 + l15;
      int cg = cb * 64 + col, b = cg >> 5, c = cg & 31;
      int tau0 = wm + mi * 16 + quad * 4;
      size_t lbase = ((size_t)(b * H_ + h)) * L_ + c * 128 + tau0;
      const f16* rp = res + lbase;
      f16x4 o;
#pragma unroll
      for (int r = 0; r < 4; ++r)
        o[r] = (f16)(acc[mi][ni][r] + Dh * (float)Vs[col * 136 + tau0 + r] + (float)rp[r]);
      *(f16x4*)(y4 + lbase) = o;
    }
}

// transpose + LayerNorm over H=768.  grid (64 l-tiles, 8 b); y4 is f16 [b,h,l]
__global__ __launch_bounds__(256) void layernorm_t(const f16* __restrict__ y4,
                                                   const float* __restrict__ gamma,
                                                   const float* __restrict__ beta,
                                                   float* __restrict__ out) {
  __shared__ f16 Ys[768 * 72];
  __shared__ float psum[256], psq[256], mu[64], rs[64];
  const int b = blockIdx.y, l0 = blockIdx.x * 64;
  const int tid = threadIdx.x;
  {
    int r8 = tid >> 3, c = tid & 7;   // 8 lanes x 16 B per 128 B row; 32 rows/iter
    for (int it = 0; it < 24; ++it) {
      int hh = it * 32 + r8;
      f16x8 x = *(const f16x8*)(y4 + ((size_t)(b * H_ + hh)) * L_ + l0 + c * 8);
      *(f16x8*)(&Ys[hh * 72 + c * 8]) = x;
    }
  }
  __syncthreads();
  {
    int l = tid & 63, hg = tid >> 6;
    float s = 0.f, s2 = 0.f;
    for (int k = 0; k < 192; ++k) {
      float val = (float)Ys[(hg * 192 + k) * 72 + l];
      s += val; s2 += val * val;
    }
    psum[hg * 64 + l] = s; psq[hg * 64 + l] = s2;
  }
  __syncthreads();
  if (tid < 64) {
    float S = 0.f, S2 = 0.f;
    for (int g = 0; g < 4; ++g) { S += psum[g * 64 + tid]; S2 += psq[g * 64 + tid]; }
    float m = S / 768.f;
    float var = S2 / 768.f - m * m;
    mu[tid] = m; rs[tid] = rsqrtf(var + 1e-5f);
  }
  __syncthreads();
  float g0 = gamma[tid], g1 = gamma[256 + tid], g2 = gamma[512 + tid];
  float be0 = beta[tid], be1 = beta[256 + tid], be2 = beta[512 + tid];
  for (int lv = 0; lv < 8; ++lv) {
    f16x8 y0 = *(const f16x8*)(&Ys[(size_t)tid * 72 + lv * 8]);
    f16x8 y1 = *(const f16x8*)(&Ys[(size_t)(256 + tid) * 72 + lv * 8]);
    f16x8 y2 = *(const f16x8*)(&Ys[(size_t)(512 + tid) * 72 + lv * 8]);
#pragma unroll
    for (int e = 0; e < 8; ++e) {
      int ll = lv * 8 + e;
      float m = mu[ll], r = rs[ll];
      size_t ob = ((size_t)b * L_ + l0 + ll) * H_;
      out[ob + tid]       = ((float)y0[e] - m) * r * g0 + be0;
      out[ob + 256 + tid] = ((float)y1[e] - m) * r * g1 + be1;
      out[ob + 512 + tid] = ((float)y2[e] - m) * r * g2 + be2;
    }
  }
}

// ---------------- launch ----------------
extern "C" void kernel_launch(void* const* d_in, const int* in_sizes, int n_in,
                              void* d_out, int out_size, void* d_ws, size_t ws_size,
                              hipStream_t stream) {
  const float* x      = (const float*)d_in[0];
  const float* cw0    = (const float*)d_in[1];
  const float* cb0    = (const float*)d_in[2];
  const float* cw1    = (const float*)d_in[3];
  const float* cb1    = (const float*)d_in[4];
  const float* cw2    = (const float*)d_in[5];
  const float* cb2    = (const float*)d_in[6];
  const float* gate_w = (const float*)d_in[7];
  const float* gate_b = (const float*)d_in[8];
  const float* res_w  = (const float*)d_in[9];
  const float* res_b  = (const float*)d_in[10];
  const float* log_dt = (const float*)d_in[11];
  const float* A_re   = (const float*)d_in[12];
  const float* A_im   = (const float*)d_in[13];
  const float* C_re   = (const float*)d_in[14];
  const float* C_im   = (const float*)d_in[15];
  const float* Dskip  = (const float*)d_in[16];
  const float* ln_g   = (const float*)d_in[17];
  const float* ln_b   = (const float*)d_in[18];
  float* out = (float*)d_out;

  char* ws = (char*)d_ws;
  f16*   xh   = (f16*)(ws + 0);            // 16,777,216
  f16*   Ac   = (f16*)(ws + 16777216);     //  3,276,800
  f16*   Ag   = (f16*)(ws + 20054016);     //    786,432 (gate_w ++ res_w)
  f16*   zbuf = (f16*)(ws + 20840448);     //      1,024
  f16*   vb   = (f16*)(ws + 20841472);     // 50,331,648
  f16*   resb = (f16*)(ws + 71173120);     // 50,331,648
  f16*   gts  = (f16*)(ws + 121504768);    // 50,331,648
  f16*   A1   = (f16*)(ws + 171836416);    // 12,582,912
  f16*   A2   = (f16*)(ws + 184419328);    // 12,582,912
  float* kT   = (float*)(ws + 197002240);  //    393,216
  float* WLc  = (float*)(ws + 197395456);  //    196,608
  f16*   Xin  = (f16*)(ws + 197592064);    // 25,165,824
  f16*   y4   = (f16*)(ws + 222757888);    // 50,331,648   (total ~273 MB)

  prep_all<<<14977, 256, 0, stream>>>(x, gate_w, res_w, cw0, cw1, cw2,
                                      xh, Ag, (float*)zbuf, Ac);
  s4_all<<<480, 256, 0, stream>>>(log_dt, A_re, A_im, C_re, C_im, A1, A2, WLc, kT);

  gemm_gr<<<dim3(256, 12), 256, 0, stream>>>(xh, Ag, gate_b, res_b, gts, resb);
  gemm_conv8<<<dim3(128, 3), 512, 0, stream>>>(xh, Ac, cb0, cb1, cb2, gts, zbuf, vb);

  s1_states<<<dim3(2, 768), 256, 0, stream>>>(vb, A1, WLc, Xin);
  s3_output<<<dim3(4, 768), 256, 0, stream>>>(vb, A2, resb, kT, Xin, Dskip, y4);

  layernorm_t<<<dim3(64, 8), 256, 0, stream>>>(y4, ln_g, ln_b, out);
}

// Round 3
// 441.834 us; speedup vs baseline: 1.0386x; 1.0267x over previous
//
#include <hip/hip_runtime.h>
#include <cstdint>
#include <cstddef>

// StripedHyena layer on MI355X.
// R8: gemm_conv rebuilt around LDS-read/MFMA overlap. R7 measured 4920
// cyc/K-step = 2483 (MFMA) + 2304 (192 ds_read_b128 @ 12cyc) SERIALIZED by
// my own per-phase lgkmcnt(0) drains. New structure: 4Mx2N wave grid, bf as
// 4 ping-pong quarter sets pipelined inside the step (each 384-cyc read burst
// hides under a 620-cyc MFMA window), af reloaded once per step, NO manual
// lgkmcnt (compiler emits fine-grained register-dep waits), ONE barrier per
// K-step, counted vmcnt(4) for the A-stage pipeline. B-resident slab + A
// triple-buffer staging kept from R7.

#define B_ 8
#define L_ 4096
#define D_ 256
#define H_ 768
#define NST 32
#define LC 128
#define NC 32

typedef _Float16 f16;
typedef _Float16 f16x8 __attribute__((ext_vector_type(8)));
typedef _Float16 f16x4 __attribute__((ext_vector_type(4)));
typedef _Float16 f16x2 __attribute__((ext_vector_type(2)));
typedef float f32x4 __attribute__((ext_vector_type(4)));

__device__ __forceinline__ f32x4 mfma16(f16x8 a, f16x8 b, f32x4 c) {
  return __builtin_amdgcn_mfma_f32_16x16x32_f16(a, b, c, 0, 0, 0);
}

#define GLDS16(g, l)                                                              \
  __builtin_amdgcn_global_load_lds((const __attribute__((address_space(1))) void*)(g), \
                                   (__attribute__((address_space(3))) void*)(l), 16, 0, 0)

// ---------------- fused prep: casts + zero buffer + conv A-matrix ----------------
__global__ __launch_bounds__(256) void prep_all(
    const float* __restrict__ x, const float* __restrict__ gate_w,
    const float* __restrict__ res_w,
    const float* __restrict__ w0, const float* __restrict__ w1, const float* __restrict__ w2,
    f16* __restrict__ xh, f16* __restrict__ Ag, float* __restrict__ zbuf,
    f16* __restrict__ A) {
  int bid = blockIdx.x, tid = threadIdx.x;
  if (bid < 8192) {            // cast x -> xh
    int i = (bid * 256 + tid) * 4;
    float4 v = *(const float4*)(x + i);
    xh[i+0]=(f16)v.x; xh[i+1]=(f16)v.y; xh[i+2]=(f16)v.z; xh[i+3]=(f16)v.w;
  } else if (bid < 8384) {     // cast gate_w
    int i = ((bid - 8192) * 256 + tid) * 4;
    float4 v = *(const float4*)(gate_w + i);
    Ag[i+0]=(f16)v.x; Ag[i+1]=(f16)v.y; Ag[i+2]=(f16)v.z; Ag[i+3]=(f16)v.w;
  } else if (bid < 8576) {     // cast res_w
    int i = ((bid - 8384) * 256 + tid) * 4;
    float4 v = *(const float4*)(res_w + i);
    f16* d = Ag + 768 * 256;
    d[i+0]=(f16)v.x; d[i+1]=(f16)v.y; d[i+2]=(f16)v.z; d[i+3]=(f16)v.w;
  } else if (bid == 8576) {    // zero buffer for OOB dilation rows
    zbuf[tid] = 0.f;
  } else {                     // conv weights -> A[o][t*256+j] layout
    int idx = (bid - 8577) * 256 + tid;   // exactly 1,638,400
    const int n0 = 256 * 256 * 3, n1 = 256 * 256 * 7;
    const float* w; int K, base;
    if (idx < n0) { w = w0; K = 3; base = 0; }
    else if (idx < n0 + n1) { idx -= n0; w = w1; K = 7; base = 256 * 768; }
    else { idx -= n0 + n1; w = w2; K = 15; base = 256 * 768 + 256 * 1792; }
    int o = idx / (256 * K); int r = idx - o * (256 * K); int j = r / K; int t = r - j * K;
    A[base + o * (256 * K) + t * 256 + j] = (f16)w[idx];
  }
}

// ---------------- fused S4D parameter build ----------------
__global__ __launch_bounds__(256) void s4_all(const float* __restrict__ log_dt,
                                              const float* __restrict__ A_re,
                                              const float* __restrict__ A_im,
                                              const float* __restrict__ C_re,
                                              const float* __restrict__ C_im,
                                              f16* __restrict__ A1, f16* __restrict__ A2,
                                              float* __restrict__ WLc,
                                              float* __restrict__ kT) {
  int bid = blockIdx.x, tid = threadIdx.x;
  if (bid < 96) {
    int idx = bid * 256 + tid;  // h*32+n
    int h = idx >> 5, n = idx & 31;
    float dt = expf(log_dt[h]);
    float Ar = A_re[idx], Ai = A_im[idx];
    float ar = dt * Ar, ai = dt * Ai;
    float e = expf(ar), sn, cs; sincosf(ai, &sn, &cs);
    float wr = e * cs, wi = e * sn;                 // w = exp(dt*A)
    float den = Ar * Ar + Ai * Ai;
    float Er = wr - 1.f, Ei = wi;
    float Cr = C_re[idx], Ci = C_im[idx];
    float nr = Cr * Er - Ci * Ei, ni = Cr * Ei + Ci * Er;
    float Cdr = (nr * Ar + ni * Ai) / den;          // C_disc = C*(w-1)/A
    float Cdi = (ni * Ar - nr * Ai) / den;
    f16* A1r = A1 + ((size_t)h * 64 + 2 * n) * LC;
    f16* A1i = A1 + ((size_t)h * 64 + 2 * n + 1) * LC;
    float pr = 1.f, pi = 0.f;
    for (int j = 0; j < LC; ++j) {
      A1r[LC - 1 - j] = (f16)pr; A1i[LC - 1 - j] = (f16)pi;
      float t0 = pr * wr - pi * wi; pi = pr * wi + pi * wr; pr = t0;
    }
    WLc[idx * 2] = pr; WLc[idx * 2 + 1] = pi;       // w^128
    float qr = wr, qi = wi;
    for (int t = 0; t < LC; ++t) {
      A2[((size_t)h * LC + t) * 64 + 2 * n]     = (f16)(2.f * (Cdr * qr - Cdi * qi));
      A2[((size_t)h * LC + t) * 64 + 2 * n + 1] = (f16)(-2.f * (Cdr * qi + Cdi * qr));
      float t0 = qr * wr - qi * wi; qi = qr * wi + qi * wr; qr = t0;
    }
  } else {
    int idx = (bid - 96) * 256 + tid;  // h*128+j
    int h = idx >> 7, j = idx & 127;
    float dt = expf(log_dt[h]);
    float acc = 0.f;
    for (int n = 0; n < NST; ++n) {
      float Ar = A_re[h * 32 + n], Ai = A_im[h * 32 + n];
      float ar = dt * Ar, ai = dt * Ai;
      float e1 = expf(ar), s1, c1; sincosf(ai, &s1, &c1);
      float wr = e1 * c1, wi = e1 * s1;
      float den = Ar * Ar + Ai * Ai;
      float Er = wr - 1.f, Ei = wi;
      float Cr = C_re[h * 32 + n], Ci = C_im[h * 32 + n];
      float nr = Cr * Er - Ci * Ei, ni = Cr * Ei + Ci * Er;
      float Cdr = (nr * Ar + ni * Ai) / den, Cdi = (ni * Ar - nr * Ai) / den;
      float ej = expf(ar * (float)j), sj, cj; sincosf(ai * (float)j, &sj, &cj);
      acc += 2.f * (Cdr * (ej * cj) - Cdi * (ej * sj));
    }
    kT[idx] = acc;
  }
}

// -------- GEMM 1: gate + res projections (K=256). grid (256, 12) --------
__global__ __launch_bounds__(256) void gemm_gr(
    const f16* __restrict__ xh, const f16* __restrict__ Agr,
    const float* __restrict__ gate_b, const float* __restrict__ res_b,
    f16* __restrict__ gts, f16* __restrict__ res) {
  __shared__ f16 As[128 * 64];
  __shared__ f16 Bs[128 * 64];
  const int mt = blockIdx.y, nt = blockIdx.x;
  const int b = nt >> 5, l0 = (nt & 31) * 128;
  const bool isg = mt < 6;
  const int hbase = (isg ? mt : mt - 6) * 128;
  const f16* Abase = Agr + (size_t)((isg ? 0 : 768) + hbase) * 256;
  const int tid = threadIdx.x;
  const int wid = tid >> 6, lane = tid & 63, l15 = lane & 15, quad = lane >> 4;
  const int wm = (wid & 1) * 64, wn = (wid >> 1) * 64;
  const int srow = (wid << 5) + (lane >> 3);
  const int sperm = ((lane & 7) ^ (lane >> 3)) << 3;
  char* AsL = (char*)As + (wid << 12);
  char* BsL = (char*)Bs + (wid << 12);
  const f16* xrow = xh + (((size_t)b * L_) << 8);

  f32x4 acc[4][4];
#pragma unroll
  for (int i = 0; i < 4; ++i)
#pragma unroll
    for (int j = 0; j < 4; ++j) acc[i][j] = (f32x4){0.f, 0.f, 0.f, 0.f};

  for (int kc = 0; kc < 4; ++kc) {
#pragma unroll
    for (int j = 0; j < 4; ++j) {
      int row = srow + j * 8;
      GLDS16(Abase + (size_t)row * 256 + kc * 64 + sperm, AsL + (j << 10));
      GLDS16(xrow + ((size_t)(l0 + row) << 8) + kc * 64 + sperm, BsL + (j << 10));
    }
    __syncthreads();
#pragma unroll
    for (int k2 = 0; k2 < 2; ++k2) {
      f16x8 af[4], bf[4];
#pragma unroll
      for (int mi = 0; mi < 4; ++mi) {
        int r = wm + mi * 16 + l15;
        af[mi] = *(const f16x8*)(&As[r * 64 + (((k2 * 4 + quad) ^ (r & 7)) << 3)]);
      }
#pragma unroll
      for (int ni = 0; ni < 4; ++ni) {
        int r = wn + ni * 16 + l15;
        bf[ni] = *(const f16x8*)(&Bs[r * 64 + (((k2 * 4 + quad) ^ (r & 7)) << 3)]);
      }
#pragma unroll
      for (int mi = 0; mi < 4; ++mi)
#pragma unroll
        for (int ni = 0; ni < 4; ++ni) acc[mi][ni] = mfma16(af[mi], bf[ni], acc[mi][ni]);
    }
    __syncthreads();
  }

  if (isg) {
#pragma unroll
    for (int mi = 0; mi < 4; ++mi)
#pragma unroll
      for (int ni = 0; ni < 4; ++ni) {
        int hg = hbase + wm + mi * 16 + quad * 4;
        int lg = l0 + wn + ni * 16 + l15;
#pragma unroll
        for (int r = 0; r < 4; ++r) {
          float val = acc[mi][ni][r] + gate_b[hg + r];
          gts[((size_t)(b * H_ + hg + r)) * L_ + lg] = (f16)(1.f / (1.f + expf(-val)));
        }
      }
  } else {
#pragma unroll
    for (int mi = 0; mi < 4; ++mi)
#pragma unroll
      for (int ni = 0; ni < 4; ++ni) {
        int hg = hbase + wm + mi * 16 + quad * 4;
        int lg = l0 + wn + ni * 16 + l15;
#pragma unroll
        for (int r = 0; r < 4; ++r)
          res[((size_t)(b * H_ + hg + r)) * L_ + lg] = (f16)(acc[mi][ni][r] + res_b[hg + r]);
      }
  }
}

// -------- GEMM 2: dilated convs, 256^2 tile, B-resident, pipelined quarters.
// grid (128, 3). 4Mx2N wave grid: per-wave 64x128. Per K-step: af (8 ds)
// loaded once; bf (4 quarters x 4 ds) ping-pong through 2 register sets,
// each read burst hidden under the previous quarter's 16-MFMA window.
// ONE barrier per step; no manual lgkmcnt (compiler emits register-dep
// waits); counted vmcnt(4) keeps the A-stage pipeline 2 deep. --------
__global__ __launch_bounds__(512, 2) void gemm_conv8(
    const f16* __restrict__ xh, const f16* __restrict__ Aconv,
    const float* __restrict__ cb0, const float* __restrict__ cb1, const float* __restrict__ cb2,
    const f16* __restrict__ gts, const f16* __restrict__ zbuf,
    f16* __restrict__ v) {
  __shared__ f16 lds[69632];     // 3 A-bufs (3*16384) + B slab (320*64) = 139,264 B
  f16* Bs = lds + 49152;

  const int nt = blockIdx.x;
  const int b = nt >> 4, l0 = (nt & 15) * 256;
  const int ci = 2 - blockIdx.y;           // heavy (taps=15) dispatched first
  const int tid = threadIdx.x;
  const int wid = tid >> 6, lane = tid & 63, l15 = lane & 15, quad = lane >> 4;
  const int wr = wid >> 1, wc = wid & 1;   // 4 (M) x 2 (N) wave grid
  const int rq = tid >> 3;                 // stage row-within-round (0..63)
  const int cswz = ((tid & 7) ^ ((tid >> 3) & 7)) << 3;  // stage src swizzle (f16)
  const f16* xrow = xh + (((size_t)b * L_) << 8);

  const f16* Acb; int Krow, taps, dil;
  if (ci == 0)      { Acb = Aconv;                          Krow = 768;  taps = 3;  dil = 1; }
  else if (ci == 1) { Acb = Aconv + 256 * 768;              Krow = 1792; taps = 7;  dil = 2; }
  else              { Acb = Aconv + 256 * 768 + 256 * 1792; Krow = 3840; taps = 15; dil = 4; }
  const int half = (taps - 1) / 2;
  const int shift0 = 32 - half * dil;      // B row shift at t=0

  f32x4 acc[4][8];                         // [mi][q*2+ni]
#pragma unroll
  for (int i = 0; i < 4; ++i)
#pragma unroll
    for (int j = 0; j < 8; ++j) acc[i][j] = (f32x4){0.f, 0.f, 0.f, 0.f};
  f16x8 af[4][2], bfA[2][2], bfB[2][2];

  // ---- stage B slab for j-block jc: 320 rows x 64 cols, 5 rounds ----
  auto stageB = [&](int jc) {
#pragma unroll
    for (int q = 0; q < 5; ++q) {
      int r = q * 64 + rq;                 // physical row 0..319
      int gl = l0 - 32 + r;
      const f16* src = (gl < 0 || gl >= L_) ? (zbuf + cswz)
                       : xrow + ((size_t)gl << 8) + jc * 64 + cswz;
      GLDS16(src, Bs + q * 4096 + wid * 512);
    }
  };
  // ---- stage a full A tile (t2, jc2) into buf: 4 glds ----
  auto stageA4 = [&](int t2, int jc2, f16* buf) {
#pragma unroll
    for (int q = 0; q < 4; ++q) {
      const f16* src = Acb + (size_t)(q * 64 + rq) * Krow + t2 * 256 + jc2 * 64 + cswz;
      GLDS16(src, buf + q * 4096 + wid * 512);
    }
  };
  auto readAF = [&](const f16* Ab) {
#pragma unroll
    for (int mi = 0; mi < 4; ++mi) {
      int r = wr * 64 + mi * 16 + l15;
#pragma unroll
      for (int k2 = 0; k2 < 2; ++k2)
        af[mi][k2] = *(const f16x8*)(Ab + r * 64 + (((k2 * 4 + quad) ^ (r & 7)) << 3));
    }
  };
  auto readBF = [&](int q, int shift, f16x8 (&bf)[2][2]) {
#pragma unroll
    for (int ni = 0; ni < 2; ++ni) {
      int r = shift + wc * 128 + q * 32 + ni * 16 + l15;   // physical B row
#pragma unroll
      for (int k2 = 0; k2 < 2; ++k2)
        bf[ni][k2] = *(const f16x8*)(Bs + r * 64 + (((k2 * 4 + quad) ^ (r & 7)) << 3));
    }
  };
  auto qMM = [&](int q, f16x8 (&bf)[2][2]) {
#pragma unroll
    for (int k2 = 0; k2 < 2; ++k2)
#pragma unroll
      for (int mi = 0; mi < 4; ++mi)
#pragma unroll
        for (int ni = 0; ni < 2; ++ni)
          acc[mi][q * 2 + ni] = mfma16(af[mi][k2], bf[ni][k2], acc[mi][q * 2 + ni]);
  };

  // ---- prologue: B(0) + A(t=0) + A(t=1), drain, prefetch bf quarter 0 ----
  stageB(0);
  stageA4(0, 0, lds);
  stageA4(1, 0, lds + 16384);
  asm volatile("s_waitcnt vmcnt(0)" ::: "memory");
  __builtin_amdgcn_s_barrier();
  readBF(0, shift0, bfA);

  int ca = 0;
#pragma unroll 1
  for (int jc = 0; jc < 4; ++jc) {
#pragma unroll 1
    for (int t = 0; t < taps; ++t) {
      const int shift = shift0 + t * dil;
      f16* Acur = lds + ca * 16384;
      int pa = ca + 2; if (pa >= 3) pa -= 3;
      f16* Apre = lds + pa * 16384;
      int t2 = t + 2, jc2 = jc;
      if (t2 >= taps) { t2 -= taps; ++jc2; }
      const bool pf = (jc2 < 4);

      // step body: af once, bf quarters ping-pong under MFMA windows
      readAF(Acur);
      readBF(1, shift, bfB);
      if (pf) stageA4(t2, jc2, Apre);
      qMM(0, bfA);
      readBF(2, shift, bfA);
      qMM(1, bfB);
      readBF(3, shift, bfB);
      qMM(2, bfA);
      qMM(3, bfB);

      if (t < taps - 1) {
        readBF(0, shift + dil, bfA);       // prefetch next step's quarter 0
        if (pf) asm volatile("s_waitcnt vmcnt(4)" ::: "memory");
        else    asm volatile("s_waitcnt vmcnt(0)" ::: "memory");
        __builtin_amdgcn_s_barrier();      // A(s+1) visible to all; step boundary
      } else if (jc < 3) {
        __builtin_amdgcn_s_barrier();      // all waves done reading old B slab
        stageB(jc + 1);
        asm volatile("s_waitcnt vmcnt(0)" ::: "memory");
        __builtin_amdgcn_s_barrier();      // new slab + all A stages visible
        readBF(0, shift0, bfA);
      }                                    // else: last step, fall through
      ca = (ca == 2) ? 0 : ca + 1;
    }
  }

  // ---- epilogue: bias + gate-mul + store (acc in regs) ----
  const float* cbias = (ci == 0) ? cb0 : (ci == 1 ? cb1 : cb2);
#pragma unroll
  for (int mi = 0; mi < 4; ++mi)
#pragma unroll
    for (int q = 0; q < 4; ++q)
#pragma unroll
      for (int ni = 0; ni < 2; ++ni) {
        int mg = wr * 64 + mi * 16 + quad * 4;
        int lg = l0 + wc * 128 + q * 32 + ni * 16 + l15;
        f32x4 a4 = acc[mi][q * 2 + ni];
#pragma unroll
        for (int r = 0; r < 4; ++r) {
          size_t a = ((size_t)(b * H_ + ci * 256 + mg + r)) * L_ + lg;
          float val = (a4[r] + cbias[mg + r]) * (float)gts[a];
          v[a] = (f16)val;
        }
      }
}

// ------- S4D: chunk end-states GEMM + fused carry scan -> Xin (f16). grid (2,768) -------
__global__ __launch_bounds__(256) void s1_states(const f16* __restrict__ v,
                                                 const f16* __restrict__ A1,
                                                 const float* __restrict__ WLc,
                                                 f16* __restrict__ Xin) {
  __shared__ f16 A1s[64 * 136];
  __shared__ f16 Vs[128 * 136];   // 34,816 B; aliased as Xls[128][68] f32 after MFMA
  const int h = blockIdx.y, cb = blockIdx.x;
  const int tid = threadIdx.x;
  {
    int row = tid >> 2, q = tid & 3;
    const f16x8* src = (const f16x8*)(A1 + ((size_t)h * 64 + row) * 128 + q * 32);
    f16x8* dst = (f16x8*)(&A1s[row * 136 + q * 32]);
    dst[0] = src[0]; dst[1] = src[1]; dst[2] = src[2]; dst[3] = src[3];
  }
  {
    int col = tid >> 1, half = tid & 1;
    int cg = cb * 128 + col, b = cg >> 5, c = cg & 31;
    const f16x8* src = (const f16x8*)(v + ((size_t)(b * H_ + h)) * L_ + c * 128 + half * 64);
    f16x8* dst = (f16x8*)(&Vs[col * 136 + half * 64]);
    dst[0] = src[0]; dst[1] = src[1]; dst[2] = src[2]; dst[3] = src[3];
    dst[4] = src[4]; dst[5] = src[5]; dst[6] = src[6]; dst[7] = src[7];
  }
  __syncthreads();
  const int wid = tid >> 6, lane = tid & 63, l15 = lane & 15, quad = lane >> 4;
  const int n0 = wid * 32;
  f32x4 acc[4][2];
#pragma unroll
  for (int i = 0; i < 4; ++i) { acc[i][0] = (f32x4){0,0,0,0}; acc[i][1] = (f32x4){0,0,0,0}; }
#pragma unroll
  for (int bk = 0; bk < 4; ++bk) {
    f16x8 af[4], bf[2];
#pragma unroll
    for (int mi = 0; mi < 4; ++mi)
      af[mi] = *(const f16x8*)(&A1s[(mi * 16 + l15) * 136 + bk * 32 + quad * 8]);
#pragma unroll
    for (int ni = 0; ni < 2; ++ni)
      bf[ni] = *(const f16x8*)(&Vs[(n0 + ni * 16 + l15) * 136 + bk * 32 + quad * 8]);
#pragma unroll
    for (int mi = 0; mi < 4; ++mi)
#pragma unroll
      for (int ni = 0; ni < 2; ++ni) acc[mi][ni] = mfma16(af[mi], bf[ni], acc[mi][ni]);
  }
  __syncthreads();                 // Vs reads complete; reuse as f32 scratch
  float* Xls = (float*)Vs;         // [col][68] f32 (exactly fits 34,816 B)
#pragma unroll
  for (int mi = 0; mi < 4; ++mi)
#pragma unroll
    for (int ni = 0; ni < 2; ++ni) {
      int col = n0 + ni * 16 + l15;
      *(f32x4*)(&Xls[col * 68 + mi * 16 + quad * 4]) = acc[mi][ni];
    }
  __syncthreads();
  if (tid < 128) {                 // one scan chain per (b4, n)
    int b4 = tid >> 5, n = tid & 31;
    int b = cb * 4 + b4;
    float Wr = WLc[(h * NST + n) * 2], Wi = WLc[(h * NST + n) * 2 + 1];
    float xr = 0.f, xi = 0.f;
    f16* xout = Xin + (((size_t)(b * H_ + h)) * NC) * 64 + 2 * n;
    for (int c = 0; c < NC; ++c) {
      float er = Xls[(b4 * 32 + c) * 68 + 2 * n];
      float ei = Xls[(b4 * 32 + c) * 68 + 2 * n + 1];
      f16x2 o; o[0] = (f16)xr; o[1] = (f16)xi;
      *(f16x2*)(xout + (size_t)c * 64) = o;    // state BEFORE chunk c
      float t = Wr * xr - Wi * xi + er;
      xi = Wr * xi + Wi * xr + ei; xr = t;
    }
  }
}

// y4 = Toeplitz(k_h) @ v_chunk + A2_h @ Xin + Dskip*v + res (f16 out). grid (4, 768)
__global__ __launch_bounds__(256) void s3_output(const f16* __restrict__ v,
                                                 const f16* __restrict__ A2g,
                                                 const f16* __restrict__ res,
                                                 const float* __restrict__ kT,
                                                 const f16* __restrict__ Xin,
                                                 const float* __restrict__ Dskip,
                                                 f16* __restrict__ y4) {
  __shared__ f16 Ts[128 * 136];   // phase2 aliases: A2s[128][72], Xs[64][72]
  __shared__ f16 Vs[64 * 136];
  __shared__ float kTs[128];
  f16* A2s = Ts;
  f16* Xs = Ts + 128 * 72;
  const int h = blockIdx.y, cb = blockIdx.x;
  const int tid = threadIdx.x;
  if (tid < 128) kTs[tid] = kT[h * 128 + tid];
  {
    int col = tid >> 2, q = tid & 3;
    int cg = cb * 64 + col, b = cg >> 5, c = cg & 31;
    const f16x8* src = (const f16x8*)(v + ((size_t)(b * H_ + h)) * L_ + c * 128 + q * 32);
    f16x8* dst = (f16x8*)(&Vs[col * 136 + q * 32]);
    dst[0] = src[0]; dst[1] = src[1]; dst[2] = src[2]; dst[3] = src[3];
  }
  __syncthreads();
  {  // build Toeplitz tile, vectorized: 8x ds_write_b128 per thread
    int tau = tid >> 1, h64 = (tid & 1) * 64;
#pragma unroll
    for (int jv = 0; jv < 8; ++jv) {
      int s0 = h64 + jv * 8;
      f16x8 w;
#pragma unroll
      for (int e = 0; e < 8; ++e) {
        int s = s0 + e;
        w[e] = (f16)((s <= tau) ? kTs[tau - s] : 0.f);
      }
      *(f16x8*)(&Ts[tau * 136 + s0]) = w;
    }
  }
  __syncthreads();
  const int wid = tid >> 6, lane = tid & 63, l15 = lane & 15, quad = lane >> 4;
  const int wm = (wid & 1) * 64, wn = (wid >> 1) * 32;
  f32x4 acc[4][2];
#pragma unroll
  for (int i = 0; i < 4; ++i) { acc[i][0] = (f32x4){0,0,0,0}; acc[i][1] = (f32x4){0,0,0,0}; }
#pragma unroll
  for (int bk = 0; bk < 4; ++bk) {
    f16x8 af[4], bf[2];
#pragma unroll
    for (int mi = 0; mi < 4; ++mi)
      af[mi] = *(const f16x8*)(&Ts[(wm + mi * 16 + l15) * 136 + bk * 32 + quad * 8]);
#pragma unroll
    for (int ni = 0; ni < 2; ++ni)
      bf[ni] = *(const f16x8*)(&Vs[(wn + ni * 16 + l15) * 136 + bk * 32 + quad * 8]);
#pragma unroll
    for (int mi = 0; mi < 4; ++mi)
#pragma unroll
      for (int ni = 0; ni < 2; ++ni) acc[mi][ni] = mfma16(af[mi], bf[ni], acc[mi][ni]);
  }
  __syncthreads();  // done with Ts; restage as A2s + Xs
  {
    int row = tid >> 1, half = tid & 1;
    const f16x8* src = (const f16x8*)(A2g + ((size_t)h * 128 + row) * 64 + half * 32);
    f16x8* dst = (f16x8*)(&A2s[row * 72 + half * 32]);
    dst[0] = src[0]; dst[1] = src[1]; dst[2] = src[2]; dst[3] = src[3];
  }
  {
    int col = tid >> 2, part = tid & 3;
    int cg = cb * 64 + col, b = cg >> 5, c = cg & 31;
    const f16x8* src = (const f16x8*)(Xin + (((size_t)(b * H_ + h)) * NC + c) * 64 + part * 16);
    f16x8* dst = (f16x8*)(&Xs[col * 72 + part * 16]);
    dst[0] = src[0]; dst[1] = src[1];
  }
  __syncthreads();
#pragma unroll
  for (int bk = 0; bk < 2; ++bk) {
    f16x8 af[4], bf[2];
#pragma unroll
    for (int mi = 0; mi < 4; ++mi)
      af[mi] = *(const f16x8*)(&A2s[(wm + mi * 16 + l15) * 72 + bk * 32 + quad * 8]);
#pragma unroll
    for (int ni = 0; ni < 2; ++ni)
      bf[ni] = *(const f16x8*)(&Xs[(wn + ni * 16 + l15) * 72 + bk * 32 + quad * 8]);
#pragma unroll
    for (int mi = 0; mi < 4; ++mi)
#pragma unroll
      for (int ni = 0; ni < 2; ++ni) acc[mi][ni] = mfma16(af[mi], bf[ni], acc[mi][ni]);
  }
  float Dh = Dskip[h];
#pragma unroll
  for (int mi = 0; mi < 4; ++mi)
#pragma unroll
    for (int ni = 0; ni < 2; ++ni) {
      int col = wn + ni * 16 + l15;
      int cg = cb * 64 + col, b = cg >> 5, c = cg & 31;
      int tau0 = wm + mi * 16 + quad * 4;
      size_t lbase = ((size_t)(b * H_ + h)) * L_ + c * 128 + tau0;
      const f16* rp = res + lbase;
      f16x4 o;
#pragma unroll
      for (int r = 0; r < 4; ++r)
        o[r] = (f16)(acc[mi][ni][r] + Dh * (float)Vs[col * 136 + tau0 + r] + (float)rp[r]);
      *(f16x4*)(y4 + lbase) = o;
    }
}

// transpose + LayerNorm over H=768.  grid (64 l-tiles, 8 b); y4 is f16 [b,h,l]
__global__ __launch_bounds__(256) void layernorm_t(const f16* __restrict__ y4,
                                                   const float* __restrict__ gamma,
                                                   const float* __restrict__ beta,
                                                   float* __restrict__ out) {
  __shared__ f16 Ys[768 * 72];
  __shared__ float psum[256], psq[256], mu[64], rs[64];
  const int b = blockIdx.y, l0 = blockIdx.x * 64;
  const int tid = threadIdx.x;
  {
    int r8 = tid >> 3, c = tid & 7;   // 8 lanes x 16 B per 128 B row; 32 rows/iter
    for (int it = 0; it < 24; ++it) {
      int hh = it * 32 + r8;
      f16x8 x = *(const f16x8*)(y4 + ((size_t)(b * H_ + hh)) * L_ + l0 + c * 8);
      *(f16x8*)(&Ys[hh * 72 + c * 8]) = x;
    }
  }
  __syncthreads();
  {
    int l = tid & 63, hg = tid >> 6;
    float s = 0.f, s2 = 0.f;
    for (int k = 0; k < 192; ++k) {
      float val = (float)Ys[(hg * 192 + k) * 72 + l];
      s += val; s2 += val * val;
    }
    psum[hg * 64 + l] = s; psq[hg * 64 + l] = s2;
  }
  __syncthreads();
  if (tid < 64) {
    float S = 0.f, S2 = 0.f;
    for (int g = 0; g < 4; ++g) { S += psum[g * 64 + tid]; S2 += psq[g * 64 + tid]; }
    float m = S / 768.f;
    float var = S2 / 768.f - m * m;
    mu[tid] = m; rs[tid] = rsqrtf(var + 1e-5f);
  }
  __syncthreads();
  float g0 = gamma[tid], g1 = gamma[256 + tid], g2 = gamma[512 + tid];
  float be0 = beta[tid], be1 = beta[256 + tid], be2 = beta[512 + tid];
  for (int lv = 0; lv < 8; ++lv) {
    f16x8 y0 = *(const f16x8*)(&Ys[(size_t)tid * 72 + lv * 8]);
    f16x8 y1 = *(const f16x8*)(&Ys[(size_t)(256 + tid) * 72 + lv * 8]);
    f16x8 y2 = *(const f16x8*)(&Ys[(size_t)(512 + tid) * 72 + lv * 8]);
#pragma unroll
    for (int e = 0; e < 8; ++e) {
      int ll = lv * 8 + e;
      float m = mu[ll], r = rs[ll];
      size_t ob = ((size_t)b * L_ + l0 + ll) * H_;
      out[ob + tid]       = ((float)y0[e] - m) * r * g0 + be0;
      out[ob + 256 + tid] = ((float)y1[e] - m) * r * g1 + be1;
      out[ob + 512 + tid] = ((float)y2[e] - m) * r * g2 + be2;
    }
  }
}

// ---------------- launch ----------------
extern "C" void kernel_launch(void* const* d_in, const int* in_sizes, int n_in,
                              void* d_out, int out_size, void* d_ws, size_t ws_size,
                              hipStream_t stream) {
  const float* x      = (const float*)d_in[0];
  const float* cw0    = (const float*)d_in[1];
  const float* cb0    = (const float*)d_in[2];
  const float* cw1    = (const float*)d_in[3];
  const float* cb1    = (const float*)d_in[4];
  const float* cw2    = (const float*)d_in[5];
  const float* cb2    = (const float*)d_in[6];
  const float* gate_w = (const float*)d_in[7];
  const float* gate_b = (const float*)d_in[8];
  const float* res_w  = (const float*)d_in[9];
  const float* res_b  = (const float*)d_in[10];
  const float* log_dt = (const float*)d_in[11];
  const float* A_re   = (const float*)d_in[12];
  const float* A_im   = (const float*)d_in[13];
  const float* C_re   = (const float*)d_in[14];
  const float* C_im   = (const float*)d_in[15];
  const float* Dskip  = (const float*)d_in[16];
  const float* ln_g   = (const float*)d_in[17];
  const float* ln_b   = (const float*)d_in[18];
  float* out = (float*)d_out;

  char* ws = (char*)d_ws;
  f16*   xh   = (f16*)(ws + 0);            // 16,777,216
  f16*   Ac   = (f16*)(ws + 16777216);     //  3,276,800
  f16*   Ag   = (f16*)(ws + 20054016);     //    786,432 (gate_w ++ res_w)
  f16*   zbuf = (f16*)(ws + 20840448);     //      1,024
  f16*   vb   = (f16*)(ws + 20841472);     // 50,331,648
  f16*   resb = (f16*)(ws + 71173120);     // 50,331,648
  f16*   gts  = (f16*)(ws + 121504768);    // 50,331,648
  f16*   A1   = (f16*)(ws + 171836416);    // 12,582,912
  f16*   A2   = (f16*)(ws + 184419328);    // 12,582,912
  float* kT   = (float*)(ws + 197002240);  //    393,216
  float* WLc  = (float*)(ws + 197395456);  //    196,608
  f16*   Xin  = (f16*)(ws + 197592064);    // 25,165,824
  f16*   y4   = (f16*)(ws + 222757888);    // 50,331,648   (total ~273 MB)

  prep_all<<<14977, 256, 0, stream>>>(x, gate_w, res_w, cw0, cw1, cw2,
                                      xh, Ag, (float*)zbuf, Ac);
  s4_all<<<480, 256, 0, stream>>>(log_dt, A_re, A_im, C_re, C_im, A1, A2, WLc, kT);

  gemm_gr<<<dim3(256, 12), 256, 0, stream>>>(xh, Ag, gate_b, res_b, gts, resb);
  gemm_conv8<<<dim3(128, 3), 512, 0, stream>>>(xh, Ac, cb0, cb1, cb2, gts, zbuf, vb);

  s1_states<<<dim3(2, 768), 256, 0, stream>>>(vb, A1, WLc, Xin);
  s3_output<<<dim3(4, 768), 256, 0, stream>>>(vb, A2, resb, kT, Xin, Dskip, y4);

  layernorm_t<<<dim3(64, 8), 256, 0, stream>>>(y4, ln_g, ln_b, out);
}